// Round 2
// baseline (918.113 us; speedup 1.0000x reference)
//
#include <hip/hip_runtime.h>

#define T_ 32
#define B_ 32
#define MAPD 517
#define P_ 256
#define FLATD (MAPD*P_)   // 132352
#define TBN (T_*B_)       // 1024

typedef unsigned short u16;
typedef unsigned int u32;

__device__ __forceinline__ float bfv(u16 u){ u32 x = ((u32)u)<<16; return __uint_as_float(x); }
__device__ __forceinline__ u16 fbf(float f){
  u32 x = __float_as_uint(f);
  return (u16)((x + 0x7fffu + ((x>>16)&1u))>>16);
}
template<bool F32> __device__ __forceinline__ float ld(const void* p, size_t i){
  if constexpr (F32) return ((const float*)p)[i];
  else               return bfv(((const u16*)p)[i]);
}

// ---- dtype probe: 1 if float inputs are fp32, 0 if bf16 ----
__global__ void k_probe(const void* img, int* flag){
  if (threadIdx.x == 0 && blockIdx.x == 0){
    const u16* u = (const u16*)img;
    int cnt = 0;
    for (int i = 0; i < 256; ++i) if (u[i] <= 0x4380u) ++cnt;  // plausible bf16 in [0,256]
    *flag = (cnt < 240) ? 1 : 0;
  }
}

// ---- K5a: previous writer + mask coefficient ----
template<bool F32> __device__ void prev_body(const int* pos, const void* done, int* prev, float* coef){
  int i = blockIdx.x*blockDim.x + threadIdx.x;
  if (i >= TBN) return;
  int t = i >> 5, b = i & 31;
  int p = pos[i*2]*16 + pos[i*2+1];
  int pv = -1;
  for (int s = t-1; s >= 0; --s){
    int n = s*32 + b;
    if (pos[n*2]*16 + pos[n*2+1] == p){ pv = s; break; }
  }
  float cf = 1.f;
  for (int s = (pv<0?0:pv+1); s <= t-1; ++s) cf *= (1.f - ld<F32>(done, s*32+b));
  prev[i] = pv; coef[i] = cf;
}
__global__ void k_prev(const int* pos, const void* done, int* prev, float* coef, const int* flag){
  if (*flag) prev_body<true>(pos,done,prev,coef); else prev_body<false>(pos,done,prev,coef);
}

// ---- K5b: last writer of each (b,p) ----
template<bool F32> __device__ void last_body(const int* pos, const void* done, int* lastw, float* lastc){
  int i = blockIdx.x*blockDim.x + threadIdx.x;
  if (i >= B_*P_) return;
  int b = i >> 8, p = i & 255;
  int lw = -1;
  for (int s = T_-1; s >= 0; --s){
    int n = s*32 + b;
    if (pos[n*2]*16 + pos[n*2+1] == p){ lw = s; break; }
  }
  float cf = 1.f;
  for (int s = (lw<0?0:lw+1); s < T_; ++s) cf *= (1.f - ld<F32>(done, s*32+b));
  lastw[i] = lw; lastc[i] = cf;
}
__global__ void k_last(const int* pos, const void* done, int* lastw, float* lastc, const int* flag){
  if (*flag) last_body<true>(pos,done,lastw,lastc); else last_body<false>(pos,done,lastw,lastc);
}

// ---- K1: conv1 3x64x64 -> 32x15x15, k8 s4, ReLU ----
template<bool F32> __device__ void conv1_body(const void* img, const void* w, const void* bias, u16* out){
  __shared__ float sImg[12288];
  __shared__ float sW[6144];
  __shared__ float sB[32];
  int n = blockIdx.x;
  for (int i = threadIdx.x; i < 12288; i += 256) sImg[i] = ld<F32>(img, (size_t)n*12288 + i);
  for (int i = threadIdx.x; i < 6144;  i += 256) sW[i]   = ld<F32>(w, i);
  if (threadIdx.x < 32) sB[threadIdx.x] = ld<F32>(bias, threadIdx.x);
  __syncthreads();
  for (int item = threadIdx.x; item < 7200; item += 256){
    int oc = item/225, pos = item - oc*225;
    int oy = pos/15, ox = pos - oy*15;
    float acc = sB[oc];
    const float* wb = sW + oc*192;
    #pragma unroll
    for (int c = 0; c < 3; ++c){
      const float* ib = sImg + c*4096 + oy*256 + ox*4;
      #pragma unroll
      for (int ky = 0; ky < 8; ++ky){
        const float* ir = ib + ky*64;
        const float* wr = wb + c*64 + ky*8;
        #pragma unroll
        for (int kx = 0; kx < 8; ++kx) acc += ir[kx]*wr[kx];
      }
    }
    out[(size_t)n*7200 + item] = fbf(fmaxf(acc, 0.f));
  }
}
__global__ __launch_bounds__(256) void k_conv1(const void* img, const void* w, const void* b, u16* out, const int* flag){
  if (*flag) conv1_body<true>(img,w,b,out); else conv1_body<false>(img,w,b,out);
}

// ---- K2: conv2 32x15x15 -> 64x6x6, k4 s2, ReLU ----
template<bool F32> __device__ void conv2_body(const u16* A, const void* w, const void* bias, u16* out){
  __shared__ float sIn[32*15*16];
  int n = blockIdx.x;
  for (int idx = threadIdx.x; idx < 7200; idx += 256){
    int c = idx/225, r = idx - c*225, iy = r/15, ix = r - iy*15;
    sIn[(c*15+iy)*16 + ix] = bfv(A[(size_t)n*7200 + idx]);
  }
  __syncthreads();
  int oc = threadIdx.x & 63, pg = threadIdx.x >> 6;
  float bv = ld<F32>(bias, oc);
  float acc[9];
  #pragma unroll
  for (int q = 0; q < 9; ++q) acc[q] = bv;
  for (int c = 0; c < 32; ++c)
    #pragma unroll
    for (int ky = 0; ky < 4; ++ky){
      size_t wo = ((size_t)(oc*32 + c)*4 + ky)*4;
      float w0 = ld<F32>(w,wo), w1 = ld<F32>(w,wo+1), w2 = ld<F32>(w,wo+2), w3 = ld<F32>(w,wo+3);
      #pragma unroll
      for (int q = 0; q < 9; ++q){
        int pos = pg*9 + q, oy = pos/6, ox = pos - oy*6;
        const float* ir = sIn + (c*15 + oy*2 + ky)*16 + ox*2;
        acc[q] += ir[0]*w0 + ir[1]*w1 + ir[2]*w2 + ir[3]*w3;
      }
    }
  #pragma unroll
  for (int q = 0; q < 9; ++q){
    int pos = pg*9 + q;
    out[(size_t)n*2304 + oc*36 + pos] = fbf(fmaxf(acc[q], 0.f));
  }
}
__global__ __launch_bounds__(256) void k_conv2(const u16* A, const void* w, const void* b, u16* out, const int* flag){
  if (*flag) conv2_body<true>(A,w,b,out); else conv2_body<false>(A,w,b,out);
}

// ---- K3: conv3 64x6x6 -> 64x4x4, k3 s1, ReLU ----
template<bool F32> __device__ void conv3_body(const u16* Bv, const void* w, const void* bias, u16* out){
  __shared__ float sIn[64*6*8];
  int n = blockIdx.x;
  for (int idx = threadIdx.x; idx < 2304; idx += 256){
    int c = idx/36, r = idx - c*36, iy = r/6, ix = r - iy*6;
    sIn[(c*6+iy)*8 + ix] = bfv(Bv[(size_t)n*2304 + idx]);
  }
  __syncthreads();
  int oc = threadIdx.x & 63, pg = threadIdx.x >> 6;
  float bv = ld<F32>(bias, oc);
  float acc[4];
  #pragma unroll
  for (int q = 0; q < 4; ++q) acc[q] = bv;
  for (int c = 0; c < 64; ++c)
    #pragma unroll
    for (int ky = 0; ky < 3; ++ky){
      size_t wo = ((size_t)(oc*64 + c)*3 + ky)*3;
      float w0 = ld<F32>(w,wo), w1 = ld<F32>(w,wo+1), w2 = ld<F32>(w,wo+2);
      #pragma unroll
      for (int q = 0; q < 4; ++q){
        int pos = pg*4 + q, oy = pos >> 2, ox = pos & 3;
        const float* ir = sIn + (c*6 + oy + ky)*8 + ox;
        acc[q] += ir[0]*w0 + ir[1]*w1 + ir[2]*w2;
      }
    }
  #pragma unroll
  for (int q = 0; q < 4; ++q){
    int pos = pg*4 + q;
    out[(size_t)n*1024 + oc*16 + pos] = fbf(fmaxf(acc[q], 0.f));
  }
}
__global__ __launch_bounds__(256) void k_conv3(const u16* Bv, const void* w, const void* b, u16* out, const int* flag){
  if (*flag) conv3_body<true>(Bv,w,b,out); else conv3_body<false>(Bv,w,b,out);
}

// ---- K4: FC 1024->512 + ReLU, append one-hot -> H (fp32 1024x517) ----
template<bool F32> __device__ void fc_body(const u16* C, const void* fw, const void* fb,
                                           const int* lact, float* H){
  __shared__ __align__(16) float sIn[4][1024];
  int n0 = blockIdx.x*4;
  for (int idx = threadIdx.x; idx < 4096; idx += 256){
    int ni = idx >> 10, k = idx & 1023;
    sIn[ni][k] = bfv(C[(size_t)(n0+ni)*1024 + k]);
  }
  __syncthreads();
  int o0 = threadIdx.x, o1 = threadIdx.x + 256;
  float acc0[4], acc1[4];
  float b0 = ld<F32>(fb,o0), b1 = ld<F32>(fb,o1);
  #pragma unroll
  for (int ni = 0; ni < 4; ++ni){ acc0[ni] = b0; acc1[ni] = b1; }
  for (int k = 0; k < 1024; k += 4){
    float a0 = ld<F32>(fw,(size_t)o0*1024+k),   a1 = ld<F32>(fw,(size_t)o0*1024+k+1);
    float a2 = ld<F32>(fw,(size_t)o0*1024+k+2), a3 = ld<F32>(fw,(size_t)o0*1024+k+3);
    float c0 = ld<F32>(fw,(size_t)o1*1024+k),   c1 = ld<F32>(fw,(size_t)o1*1024+k+1);
    float c2 = ld<F32>(fw,(size_t)o1*1024+k+2), c3 = ld<F32>(fw,(size_t)o1*1024+k+3);
    #pragma unroll
    for (int ni = 0; ni < 4; ++ni){
      float4 v = ((const float4*)sIn[ni])[k>>2];
      acc0[ni] += v.x*a0 + v.y*a1 + v.z*a2 + v.w*a3;
      acc1[ni] += v.x*c0 + v.y*c1 + v.z*c2 + v.w*c3;
    }
  }
  #pragma unroll
  for (int ni = 0; ni < 4; ++ni){
    H[(size_t)(n0+ni)*MAPD + o0] = fmaxf(acc0[ni], 0.f);
    H[(size_t)(n0+ni)*MAPD + o1] = fmaxf(acc1[ni], 0.f);
  }
  if (threadIdx.x < 20){
    int ni = threadIdx.x/5, a = threadIdx.x - ni*5;
    H[(size_t)(n0+ni)*MAPD + 512 + a] = (lact[n0+ni] == a) ? 1.f : 0.f;
  }
}
__global__ __launch_bounds__(256) void k_fc(const u16* C, const void* fw, const void* fb,
                                            const int* lact, float* H, const int* flag){
  if (*flag) fc_body<true>(C,fw,fb,lact,H); else fc_body<false>(C,fw,fb,lact,H);
}

// ---- K0: transpose w1 (128 x 132352) into wt[p][c][j] (bf16) ----
template<bool F32> __device__ void wt_body(const void* pw1, const void* vw1, u16* wt){
  int c  = blockIdx.x >> 1;
  int ph = blockIdx.x & 1;
  __shared__ u16 tile[128*129];
  for (int idx = threadIdx.x; idx < 16384; idx += 256){
    int j = idx >> 7, pp = idx & 127;
    const void* w = (j < 64) ? pw1 : vw1;
    int jj = (j < 64) ? j : j - 64;
    tile[pp*129 + j] = fbf(ld<F32>(w, (size_t)jj*FLATD + c*P_ + ph*128 + pp));
  }
  __syncthreads();
  for (int idx = threadIdx.x; idx < 16384; idx += 256){
    int pp = idx >> 7, j = idx & 127;
    int p = ph*128 + pp;
    wt[((size_t)p*MAPD + c)*128 + j] = tile[pp*129 + j];
  }
}
__global__ __launch_bounds__(256) void k_wt(const void* pw1, const void* vw1, u16* wt, const int* flag){
  if (*flag) wt_body<true>(pw1,vw1,wt); else wt_body<false>(pw1,vw1,wt);
}

// ---- K6: y_init partials: state0 . w1 per p-cell ----
template<bool F32> __device__ void yinit_body(const void* st0, const u16* wt, float* part){
  int p  = blockIdx.x >> 1;
  int bh = blockIdx.x & 1;
  __shared__ float s0[MAPD][16];
  for (int idx = threadIdx.x; idx < MAPD*16; idx += 128){
    int c = idx >> 4, i = idx & 15;
    int b = bh*16 + i;
    s0[c][i] = ld<F32>(st0, ((size_t)b*MAPD + c)*256 + p);
  }
  __syncthreads();
  int j = threadIdx.x;
  float acc[16];
  #pragma unroll
  for (int i = 0; i < 16; ++i) acc[i] = 0.f;
  for (int c = 0; c < MAPD; ++c){
    float w = bfv(wt[((size_t)p*MAPD + c)*128 + j]);
    #pragma unroll
    for (int i = 0; i < 16; ++i) acc[i] += s0[c][i]*w;
  }
  #pragma unroll
  for (int i = 0; i < 16; ++i)
    part[((size_t)p*32 + bh*16 + i)*128 + j] = acc[i];
}
__global__ __launch_bounds__(128) void k_yinit(const void* st0, const u16* wt, float* part, const int* flag){
  if (*flag) yinit_body<true>(st0,wt,part); else yinit_body<false>(st0,wt,part);
}

__global__ void k_yred(const float* __restrict__ part, float* __restrict__ yi){
  int i = blockIdx.x*blockDim.x + threadIdx.x;
  if (i >= 4096) return;
  float s = 0.f;
  for (int p = 0; p < 256; ++p) s += part[(size_t)p*4096 + i];
  yi[i] = s;
}

// ---- K7: per-(t,b,j) delta dot-products ----
template<bool F32> __device__ void delta_body(const float* H, const u16* wt, const void* st0,
                                              const int* pos, const void* done,
                                              const int* prev, const float* coef, float* dlt){
  int n = blockIdx.x;
  int b = n & 31;
  int p = pos[n*2]*16 + pos[n*2+1];
  float m = 1.f - ld<F32>(done, n);
  int pv = prev[n];
  float cf = coef[n]*m;
  __shared__ float diff[MAPD];
  const float* hc = H + (size_t)n*MAPD;
  for (int c = threadIdx.x; c < MAPD; c += 128){
    float old;
    if (pv >= 0) old = H[(size_t)(pv*32 + b)*MAPD + c];
    else         old = ld<F32>(st0, ((size_t)b*MAPD + c)*256 + p);
    diff[c] = hc[c] - cf*old;
  }
  __syncthreads();
  int j = threadIdx.x;
  float acc = 0.f;
  for (int c = 0; c < MAPD; ++c)
    acc += diff[c]*bfv(wt[((size_t)p*MAPD + c)*128 + j]);
  dlt[(size_t)n*128 + j] = acc;
}
__global__ __launch_bounds__(128) void k_delta(const float* H, const u16* wt, const void* st0,
                                               const int* pos, const void* done,
                                               const int* prev, const float* coef, float* dlt,
                                               const int* flag){
  if (*flag) delta_body<true>(H,wt,st0,pos,done,prev,coef,dlt);
  else       delta_body<false>(H,wt,st0,pos,done,prev,coef,dlt);
}

// ---- K8: 32-step scan + head matvecs ----
template<bool F32> __device__ void scan_body(const float* yi, const float* dlt, const void* done,
                                             const void* pb1, const void* vb1,
                                             const void* pw2, const void* pb2,
                                             const void* vw2, const void* vb2, void* out){
  int b = blockIdx.x, j = threadIdx.x;
  __shared__ float th[128];
  float y = yi[b*128 + j];
  float bias = (j < 64) ? ld<F32>(pb1, j) : ld<F32>(vb1, j-64);
  for (int t = 0; t < T_; ++t){
    int n = t*32 + b;
    float m = 1.f - ld<F32>(done, n);
    y = m*y + dlt[(size_t)n*128 + j];
    th[j] = tanhf(y + bias);
    __syncthreads();
    if (j < 5){
      float s = ld<F32>(pb2, j);
      for (int q = 0; q < 64; ++q) s += th[q]*ld<F32>(pw2, j*64 + q);
      if constexpr (F32) ((float*)out)[n*5 + j] = s; else ((u16*)out)[n*5 + j] = fbf(s);
    } else if (j == 5){
      float s = ld<F32>(vb2, 0);
      for (int q = 0; q < 64; ++q) s += th[64 + q]*ld<F32>(vw2, q);
      if constexpr (F32) ((float*)out)[5120 + n] = s; else ((u16*)out)[5120 + n] = fbf(s);
    }
    __syncthreads();
  }
}
__global__ __launch_bounds__(128) void k_scan(const float* yi, const float* dlt, const void* done,
                                              const void* pb1, const void* vb1,
                                              const void* pw2, const void* pb2,
                                              const void* vw2, const void* vb2, void* out,
                                              const int* flag){
  if (*flag) scan_body<true>(yi,dlt,done,pb1,vb1,pw2,pb2,vw2,vb2,out);
  else       scan_body<false>(yi,dlt,done,pb1,vb1,pw2,pb2,vw2,vb2,out);
}

// ---- K9: final_state closed form ----
template<bool F32> __device__ void final_body(const float* H, const void* st0,
                                              const int* lastw, const float* lastc, void* out){
  size_t i = (size_t)blockIdx.x*256 + threadIdx.x;
  if (i >= (size_t)B_*FLATD) return;
  int b = (int)(i / FLATD);
  int r = (int)(i - (size_t)b*FLATD);
  int c = r >> 8, p = r & 255;
  int lw = lastw[b*256 + p];
  float lc = lastc[b*256 + p];
  float v;
  if (lw >= 0) v = H[(size_t)(lw*32 + b)*MAPD + c]*lc;
  else         v = ld<F32>(st0, i)*lc;
  if constexpr (F32) ((float*)out)[6144 + i] = v; else ((u16*)out)[6144 + i] = fbf(v);
}
__global__ __launch_bounds__(256) void k_final(const float* H, const void* st0,
                                               const int* lastw, const float* lastc, void* out,
                                               const int* flag){
  if (*flag) final_body<true>(H,st0,lastw,lastc,out); else final_body<false>(H,st0,lastw,lastc,out);
}

extern "C" void kernel_launch(void* const* d_in, const int* in_sizes, int n_in,
                              void* d_out, int out_size, void* d_ws, size_t ws_size,
                              hipStream_t stream) {
  (void)in_sizes; (void)n_in; (void)out_size; (void)ws_size;
  const void* image = d_in[0];
  const int*  lact  = (const int*)d_in[1];
  const int*  pos   = (const int*)d_in[2];
  const void* done  = d_in[3];
  const void* st0   = d_in[4];
  const void* c1w = d_in[5];  const void* c1b = d_in[6];
  const void* c2w = d_in[7];  const void* c2b = d_in[8];
  const void* c3w = d_in[9];  const void* c3b = d_in[10];
  const void* fcw = d_in[11]; const void* fcb = d_in[12];
  const void* pw1 = d_in[13]; const void* pb1 = d_in[14];
  const void* pw2 = d_in[15]; const void* pb2 = d_in[16];
  const void* vw1 = d_in[17]; const void* vb1 = d_in[18];
  const void* vw2 = d_in[19]; const void* vb2 = d_in[20];
  char* ws = (char*)d_ws;

  // Overlaid workspace (~39 MB):
  //   [0 .. 33.9MB)  WT (w1^T bf16), written AFTER convs; overlays A/Bv/C during conv phase
  u16*   WT    = (u16*)  (ws + 0);
  u16*   A     = (u16*)  (ws + 0);           // conv1 out bf16 1024*7200 (dead after conv2)
  u16*   Bv    = (u16*)  (ws + 14745600);    // conv2 out bf16 1024*2304 (dead after conv3)
  u16*   C     = (u16*)  (ws + 19464192);    // conv3 out bf16 1024*1024 (dead after fc)
  float* H     = (float*)(ws + 33882368);    // fp32 1024*517
  float* PART  = (float*)(ws + 36000256);    // fp32 256*32*128
  float* YI    = (float*)(ws + 40194560);    // fp32 32*128
  float* DLT   = (float*)(ws + 40210944);    // fp32 1024*128
  int*   PREV  = (int*)  (ws + 40735232);
  float* COEF  = (float*)(ws + 40739328);
  int*   LASTW = (int*)  (ws + 40743424);
  float* LASTC = (float*)(ws + 40776192);
  int*   FLAG  = (int*)  (ws + 40808960);

  k_probe<<<1, 64, 0, stream>>>(image, FLAG);
  k_prev <<<4, 256, 0, stream>>>(pos, done, PREV, COEF, FLAG);
  k_last <<<32, 256, 0, stream>>>(pos, done, LASTW, LASTC, FLAG);
  k_conv1<<<1024, 256, 0, stream>>>(image, c1w, c1b, A, FLAG);
  k_conv2<<<1024, 256, 0, stream>>>(A, c2w, c2b, Bv, FLAG);
  k_conv3<<<1024, 256, 0, stream>>>(Bv, c3w, c3b, C, FLAG);
  k_fc   <<<256, 256, 0, stream>>>(C, fcw, fcb, lact, H, FLAG);
  k_wt   <<<1034, 256, 0, stream>>>(pw1, vw1, WT, FLAG);   // after fc: overlays A/Bv/C
  k_yinit<<<512, 128, 0, stream>>>(st0, WT, PART, FLAG);
  k_yred <<<16, 256, 0, stream>>>(PART, YI);
  k_delta<<<1024, 128, 0, stream>>>(H, WT, st0, pos, done, PREV, COEF, DLT, FLAG);
  k_scan <<<32, 128, 0, stream>>>(YI, DLT, done, pb1, vb1, pw2, pb2, vw2, vb2, d_out, FLAG);
  k_final<<<16544, 256, 0, stream>>>(H, st0, LASTW, LASTC, d_out, FLAG);
}

// Round 3
// 784.805 us; speedup vs baseline: 1.1699x; 1.1699x over previous
//
#include <hip/hip_runtime.h>

#define T_ 32
#define B_ 32
#define MAPD 517
#define P_ 256
#define FLATD (MAPD*P_)   // 132352
#define TBN (T_*B_)       // 1024

typedef unsigned short u16;
typedef unsigned int u32;

__device__ __forceinline__ float bfv(u16 u){ u32 x = ((u32)u)<<16; return __uint_as_float(x); }
__device__ __forceinline__ u16 fbf(float f){
  u32 x = __float_as_uint(f);
  return (u16)((x + 0x7fffu + ((x>>16)&1u))>>16);
}
template<bool F32> __device__ __forceinline__ float ld(const void* p, size_t i){
  if constexpr (F32) return ((const float*)p)[i];
  else               return bfv(((const u16*)p)[i]);
}

// ---- dtype probe: 1 if float inputs are fp32, 0 if bf16 ----
__global__ void k_probe(const void* img, int* flag){
  if (threadIdx.x == 0 && blockIdx.x == 0){
    const u16* u = (const u16*)img;
    int cnt = 0;
    for (int i = 0; i < 256; ++i) if (u[i] <= 0x4380u) ++cnt;
    *flag = (cnt < 240) ? 1 : 0;
  }
}

// ---- weight prep: transpose conv weights to k-major bf16; permute fc weights ----
// W1T[k*32+oc]=c1w[oc*192+k]; W2T[k*64+oc]=c2w[oc*512+k]; W3T[k*64+oc]=c3w[oc*576+k];
// FWT[kk*512+o]=fcw[o*1024 + (kk&63)*16 + (kk>>6)]   (kk = pos*64 + c storage order)
__global__ void k_wprep(const void* c1w, const void* c2w, const void* c3w, const void* fcw,
                        u16* W1T, u16* W2T, u16* W3T, u16* FWT, const int* flag){
  bool f32 = (*flag != 0);
  int bid = blockIdx.x;
  if (bid < 24){
    int idx = bid*256 + threadIdx.x;           // 6144
    int k = idx >> 5, oc = idx & 31;
    float v = f32 ? ((const float*)c1w)[oc*192+k] : bfv(((const u16*)c1w)[oc*192+k]);
    W1T[idx] = fbf(v);
  } else if (bid < 24+128){
    int idx = (bid-24)*256 + threadIdx.x;      // 32768
    int k = idx >> 6, oc = idx & 63;
    float v = f32 ? ((const float*)c2w)[oc*512+k] : bfv(((const u16*)c2w)[oc*512+k]);
    W2T[idx] = fbf(v);
  } else if (bid < 24+128+144){
    int idx = (bid-152)*256 + threadIdx.x;     // 36864
    int k = idx >> 6, oc = idx & 63;
    float v = f32 ? ((const float*)c3w)[oc*576+k] : bfv(((const u16*)c3w)[oc*576+k]);
    W3T[idx] = fbf(v);
  } else {
    int idx = (bid-296)*256 + threadIdx.x;     // 524288
    int kk = idx >> 9, o = idx & 511;
    int k = (kk & 63)*16 + (kk >> 6);
    float v = f32 ? ((const float*)fcw)[o*1024+k] : bfv(((const u16*)fcw)[o*1024+k]);
    FWT[idx] = fbf(v);
  }
}

// ---- K5a: previous writer + mask coefficient + one-hot into H ----
template<bool F32> __device__ void prev_body(const int* pos, const void* done, const int* lact,
                                             int* prev, float* coef, float* H){
  int i = blockIdx.x*blockDim.x + threadIdx.x;
  if (i >= TBN) return;
  int t = i >> 5, b = i & 31;
  int p = pos[i*2]*16 + pos[i*2+1];
  int pv = -1;
  for (int s = t-1; s >= 0; --s){
    int n = s*32 + b;
    if (pos[n*2]*16 + pos[n*2+1] == p){ pv = s; break; }
  }
  float cf = 1.f;
  for (int s = (pv<0?0:pv+1); s <= t-1; ++s) cf *= (1.f - ld<F32>(done, s*32+b));
  prev[i] = pv; coef[i] = cf;
  int la = lact[i];
  #pragma unroll
  for (int a = 0; a < 5; ++a) H[(size_t)i*MAPD + 512 + a] = (la == a) ? 1.f : 0.f;
}
__global__ void k_prev(const int* pos, const void* done, const int* lact,
                       int* prev, float* coef, float* H, const int* flag){
  if (*flag) prev_body<true>(pos,done,lact,prev,coef,H); else prev_body<false>(pos,done,lact,prev,coef,H);
}

// ---- K5b: last writer of each (b,p) ----
template<bool F32> __device__ void last_body(const int* pos, const void* done, int* lastw, float* lastc){
  int i = blockIdx.x*blockDim.x + threadIdx.x;
  if (i >= B_*P_) return;
  int b = i >> 8, p = i & 255;
  int lw = -1;
  for (int s = T_-1; s >= 0; --s){
    int n = s*32 + b;
    if (pos[n*2]*16 + pos[n*2+1] == p){ lw = s; break; }
  }
  float cf = 1.f;
  for (int s = (lw<0?0:lw+1); s < T_; ++s) cf *= (1.f - ld<F32>(done, s*32+b));
  lastw[i] = lw; lastc[i] = cf;
}
__global__ void k_last(const int* pos, const void* done, int* lastw, float* lastc, const int* flag){
  if (*flag) last_body<true>(pos,done,lastw,lastc); else last_body<false>(pos,done,lastw,lastc);
}

// ---- K1: conv1 3x64x64 -> 32ch x 15x15, k8 s4, ReLU. out[n][pos][oc] ----
template<bool F32> __device__ void conv1_body(const void* img, const u16* w1t, const void* bias,
                                              u16* out, float* sImg, float* sWT, float* sB){
  int n = blockIdx.x, tid = threadIdx.x;
  if constexpr (F32){
    const float4* ip = (const float4*)((const float*)img + (size_t)n*12288);
    float4* sp = (float4*)sImg;
    for (int i = tid; i < 3072; i += 256) sp[i] = ip[i];
  } else {
    const ushort4* ip = (const ushort4*)((const u16*)img + (size_t)n*12288);
    for (int i = tid; i < 3072; i += 256){
      ushort4 u = ip[i];
      sImg[i*4+0] = bfv(u.x); sImg[i*4+1] = bfv(u.y);
      sImg[i*4+2] = bfv(u.z); sImg[i*4+3] = bfv(u.w);
    }
  }
  for (int i = tid; i < 6144; i += 256) sWT[i] = bfv(w1t[i]);
  if (tid < 32) sB[tid] = ld<F32>(bias, tid);
  __syncthreads();

  int oc = tid & 31, pg = tid >> 5;   // wave = 2 pg-groups x 32 oc
  float bv = sB[oc];
  float acc[2][15];
  #pragma unroll
  for (int a = 0; a < 2; ++a)
    #pragma unroll
    for (int x = 0; x < 15; ++x) acc[a][x] = bv;

  float wreg[64];
  for (int c = 0; c < 3; ++c){
    #pragma unroll
    for (int j = 0; j < 64; ++j) wreg[j] = sWT[(c*64+j)*32 + oc];   // lane-distinct banks
    #pragma unroll
    for (int oyi = 0; oyi < 2; ++oyi){
      int oy = pg + oyi*8;
      if (oy > 14) continue;
      for (int ky = 0; ky < 8; ++ky){
        const float4* rp = (const float4*)(sImg + c*4096 + (oy*4+ky)*64); // broadcast reads
        float4 row[16];
        #pragma unroll
        for (int r = 0; r < 16; ++r) row[r] = rp[r];
        #pragma unroll
        for (int ox = 0; ox < 15; ++ox){
          float4 lo = row[ox], hi = row[ox+1];
          acc[oyi][ox] += lo.x*wreg[ky*8+0] + lo.y*wreg[ky*8+1] + lo.z*wreg[ky*8+2] + lo.w*wreg[ky*8+3]
                        + hi.x*wreg[ky*8+4] + hi.y*wreg[ky*8+5] + hi.z*wreg[ky*8+6] + hi.w*wreg[ky*8+7];
        }
      }
    }
  }
  u16* ob = out + (size_t)n*7200;
  #pragma unroll
  for (int oyi = 0; oyi < 2; ++oyi){
    int oy = pg + oyi*8;
    if (oy > 14) continue;
    #pragma unroll
    for (int ox = 0; ox < 15; ++ox)
      ob[(oy*15+ox)*32 + oc] = fbf(fmaxf(acc[oyi][ox], 0.f));   // lanes oc: coalesced
  }
}
__global__ __launch_bounds__(256,2) void k_conv1(const void* img, const u16* w1t, const void* bias,
                                                 u16* out, const int* flag){
  __shared__ float smem[12288 + 6144 + 32];   // 73.9 KB, single copy
  float* sImg = smem; float* sWT = smem + 12288; float* sB = smem + 18432;
  if (*flag) conv1_body<true>(img,w1t,bias,out,sImg,sWT,sB);
  else       conv1_body<false>(img,w1t,bias,out,sImg,sWT,sB);
}

// ---- K2: conv2 32x15x15 -> 64ch x 6x6, k4 s2, ReLU. in[n][pos][c], out[n][pos][oc] ----
template<bool F32> __device__ void conv2_body(const u16* A, const u16* w2t, const void* bias,
                                              u16* out, float* sIn, u16* sW){
  int n = blockIdx.x, tid = threadIdx.x;
  const u16* ip = A + (size_t)n*7200;
  for (int idx = tid; idx < 7200; idx += 256){
    int p = idx >> 5, c = idx & 31;
    int iy = p/15, ix = p - iy*15;
    sIn[(c*15+iy)*16 + ix] = bfv(ip[idx]);
  }
  int oc = tid & 63, pg = tid >> 6;   // wave = uniform pg, 64 oc
  int oyA[9], oxA[9];
  #pragma unroll
  for (int q = 0; q < 9; ++q){ int pq = pg*9+q; oyA[q] = pq/6; oxA[q] = pq - oyA[q]*6; }
  float acc[9];
  float bv = ld<F32>(bias, oc);
  #pragma unroll
  for (int q = 0; q < 9; ++q) acc[q] = bv;

  const ushort4* wsrc = (const ushort4*)w2t;
  for (int ch = 0; ch < 4; ++ch){           // 8 input channels per chunk
    __syncthreads();
    ushort4* swp = (ushort4*)sW;
    for (int i = tid; i < 2048; i += 256) swp[i] = wsrc[ch*2048 + i];
    __syncthreads();
    for (int c = 0; c < 8; ++c){
      float wv[16];
      #pragma unroll
      for (int j = 0; j < 16; ++j) wv[j] = bfv(sW[(c*16+j)*64 + oc]);
      int cg = (ch*8 + c)*15;
      #pragma unroll
      for (int ky = 0; ky < 4; ++ky){
        #pragma unroll
        for (int q = 0; q < 9; ++q){
          const float* rw = sIn + (cg + oyA[q]*2 + ky)*16 + oxA[q]*2;  // full-wave broadcast
          acc[q] += rw[0]*wv[ky*4+0] + rw[1]*wv[ky*4+1] + rw[2]*wv[ky*4+2] + rw[3]*wv[ky*4+3];
        }
      }
    }
  }
  u16* ob = out + (size_t)n*2304;
  #pragma unroll
  for (int q = 0; q < 9; ++q)
    ob[(pg*9+q)*64 + oc] = fbf(fmaxf(acc[q], 0.f));
}
__global__ __launch_bounds__(256) void k_conv2(const u16* A, const u16* w2t, const void* bias,
                                               u16* out, const int* flag){
  __shared__ float sIn[32*15*16];      // 30 KB
  __shared__ u16   sW[8*16*64];        // 16 KB
  if (*flag) conv2_body<true>(A,w2t,bias,out,sIn,sW);
  else       conv2_body<false>(A,w2t,bias,out,sIn,sW);
}

// ---- K3: conv3 64x6x6 -> 64ch x 4x4, k3 s1, ReLU. in[n][pos][c], out[n][pos][oc] ----
template<bool F32> __device__ void conv3_body(const u16* Bv, const u16* w3t, const void* bias,
                                              u16* out, float* sIn, u16* sW){
  int n = blockIdx.x, tid = threadIdx.x;
  const u16* ip = Bv + (size_t)n*2304;
  for (int idx = tid; idx < 2304; idx += 256){
    int p = idx >> 6, c = idx & 63;
    int iy = p/6, ix = p - iy*6;
    sIn[(c*6+iy)*8 + ix] = bfv(ip[idx]);
  }
  int oc = tid & 63, pg = tid >> 6;   // oy = pg, ox = q
  float acc[4];
  float bv = ld<F32>(bias, oc);
  #pragma unroll
  for (int q = 0; q < 4; ++q) acc[q] = bv;

  const ushort4* wsrc = (const ushort4*)w3t;
  for (int ch = 0; ch < 4; ++ch){           // 16 input channels per chunk
    __syncthreads();
    ushort4* swp = (ushort4*)sW;
    for (int i = tid; i < 2304; i += 256) swp[i] = wsrc[ch*2304 + i];
    __syncthreads();
    for (int c = 0; c < 16; ++c){
      float wv[9];
      #pragma unroll
      for (int j = 0; j < 9; ++j) wv[j] = bfv(sW[(c*9+j)*64 + oc]);
      int cc = ch*16 + c;
      #pragma unroll
      for (int ky = 0; ky < 3; ++ky){
        const float4* rp = (const float4*)(sIn + (cc*6 + pg + ky)*8);  // broadcast
        float4 r0 = rp[0], r1 = rp[1];
        float rr[8] = {r0.x,r0.y,r0.z,r0.w,r1.x,r1.y,r1.z,r1.w};
        #pragma unroll
        for (int q = 0; q < 4; ++q)
          acc[q] += rr[q]*wv[ky*3+0] + rr[q+1]*wv[ky*3+1] + rr[q+2]*wv[ky*3+2];
      }
    }
  }
  u16* ob = out + (size_t)n*1024;
  #pragma unroll
  for (int q = 0; q < 4; ++q)
    ob[(pg*4+q)*64 + oc] = fbf(fmaxf(acc[q], 0.f));
}
__global__ __launch_bounds__(256) void k_conv3(const u16* Bv, const u16* w3t, const void* bias,
                                               u16* out, const int* flag){
  __shared__ float sIn[64*6*8];        // 12 KB
  __shared__ u16   sW[16*9*64];        // 18 KB
  if (*flag) conv3_body<true>(Bv,w3t,bias,out,sIn,sW);
  else       conv3_body<false>(Bv,w3t,bias,out,sIn,sW);
}

// ---- K4: fc GEMM 1024x512x1024 + ReLU -> H[samp][517] fp32 ----
// C layout [n][kk] (kk = pos*64+c), FWT [kk][512]. Tile 32 samp x 64 out per block.
template<bool F32> __device__ void fc_body(const u16* C, const u16* FWT, const void* fb,
                                           float* H, u16* sA, u16* sB){
  int tid = threadIdx.x;
  int s0 = (blockIdx.x >> 3)*32, o0 = (blockIdx.x & 7)*64;
  int si = tid & 15, ojg = tid >> 4;
  float acc[2][4];
  #pragma unroll
  for (int a = 0; a < 2; ++a)
    #pragma unroll
    for (int j = 0; j < 4; ++j) acc[a][j] = 0.f;

  for (int kc = 0; kc < 8; ++kc){
    __syncthreads();
    // stage A: 32 samp x 128 k, transposed to sA[k][34-padded]
    for (int it = 0; it < 16; ++it){
      int idx = it*256 + tid;
      int s = idx >> 7, kk = idx & 127;
      sA[kk*34 + s] = C[(size_t)(s0+s)*1024 + kc*128 + kk];
    }
    // stage B: 128 k x 64 out
    for (int it = 0; it < 32; ++it){
      int idx = it*256 + tid;
      int kk = idx >> 6, oj = idx & 63;
      sB[kk*64 + oj] = FWT[(size_t)(kc*128+kk)*512 + o0 + oj];
    }
    __syncthreads();
    for (int k = 0; k < 128; ++k){
      ushort2 a2 = *(const ushort2*)(sA + k*34 + si*2);
      ushort4 b4 = *(const ushort4*)(sB + k*64 + ojg*4);
      float a0 = bfv(a2.x), a1 = bfv(a2.y);
      float b0 = bfv(b4.x), b1 = bfv(b4.y), b2 = bfv(b4.z), b3 = bfv(b4.w);
      acc[0][0] += a0*b0; acc[0][1] += a0*b1; acc[0][2] += a0*b2; acc[0][3] += a0*b3;
      acc[1][0] += a1*b0; acc[1][1] += a1*b1; acc[1][2] += a1*b2; acc[1][3] += a1*b3;
    }
  }
  #pragma unroll
  for (int ss = 0; ss < 2; ++ss)
    #pragma unroll
    for (int j = 0; j < 4; ++j){
      int o = o0 + ojg*4 + j;
      H[(size_t)(s0 + si*2 + ss)*MAPD + o] = fmaxf(acc[ss][j] + ld<F32>(fb, o), 0.f);
    }
}
__global__ __launch_bounds__(256) void k_fc(const u16* C, const u16* FWT, const void* fb,
                                            float* H, const int* flag){
  __shared__ u16 sA[128*34];
  __shared__ u16 sB[128*64];
  if (*flag) fc_body<true>(C,FWT,fb,H,sA,sB); else fc_body<false>(C,FWT,fb,H,sA,sB);
}

// ---- K0: transpose w1 (128 x 132352) into WT[p][c][j] bf16 ----
template<bool F32> __device__ void wt_body(const void* pw1, const void* vw1, u16* wt, u16* tile){
  int c  = blockIdx.x >> 1;
  int ph = blockIdx.x & 1;
  for (int idx = threadIdx.x; idx < 16384; idx += 256){
    int j = idx >> 7, pp = idx & 127;
    const void* w = (j < 64) ? pw1 : vw1;
    int jj = (j < 64) ? j : j - 64;
    tile[pp*129 + j] = fbf(ld<F32>(w, (size_t)jj*FLATD + c*P_ + ph*128 + pp));
  }
  __syncthreads();
  for (int idx = threadIdx.x; idx < 16384; idx += 256){
    int pp = idx >> 7, j = idx & 127;
    int p = ph*128 + pp;
    wt[((size_t)p*MAPD + c)*128 + j] = tile[pp*129 + j];
  }
}
__global__ __launch_bounds__(256) void k_wt(const void* pw1, const void* vw1, u16* wt, const int* flag){
  __shared__ u16 tile[128*129];
  if (*flag) wt_body<true>(pw1,vw1,wt,tile); else wt_body<false>(pw1,vw1,wt,tile);
}

// ---- K6: y_init partials: state0 . w1 per p-cell ----
template<bool F32> __device__ void yinit_body(const void* st0, const u16* wt, float* part, float* s0){
  int p  = blockIdx.x >> 1;
  int bh = blockIdx.x & 1;
  for (int idx = threadIdx.x; idx < MAPD*16; idx += 128){
    int c = idx >> 4, i = idx & 15;
    int b = bh*16 + i;
    s0[c*16+i] = ld<F32>(st0, ((size_t)b*MAPD + c)*256 + p);
  }
  __syncthreads();
  int j = threadIdx.x;
  float acc[16];
  #pragma unroll
  for (int i = 0; i < 16; ++i) acc[i] = 0.f;
  for (int c = 0; c < MAPD; ++c){
    float w = bfv(wt[((size_t)p*MAPD + c)*128 + j]);
    const float4* s4 = (const float4*)(s0 + c*16);
    float4 v0 = s4[0], v1 = s4[1], v2 = s4[2], v3 = s4[3];
    acc[0] += v0.x*w; acc[1] += v0.y*w; acc[2] += v0.z*w; acc[3] += v0.w*w;
    acc[4] += v1.x*w; acc[5] += v1.y*w; acc[6] += v1.z*w; acc[7] += v1.w*w;
    acc[8] += v2.x*w; acc[9] += v2.y*w; acc[10] += v2.z*w; acc[11] += v2.w*w;
    acc[12] += v3.x*w; acc[13] += v3.y*w; acc[14] += v3.z*w; acc[15] += v3.w*w;
  }
  #pragma unroll
  for (int i = 0; i < 16; ++i)
    part[((size_t)p*32 + bh*16 + i)*128 + j] = acc[i];
}
__global__ __launch_bounds__(128) void k_yinit(const void* st0, const u16* wt, float* part, const int* flag){
  __shared__ float s0[MAPD*16];
  if (*flag) yinit_body<true>(st0,wt,part,s0); else yinit_body<false>(st0,wt,part,s0);
}

__global__ void k_yred(const float* __restrict__ part, float* __restrict__ yi){
  int i = blockIdx.x*blockDim.x + threadIdx.x;
  if (i >= 4096) return;
  float s = 0.f;
  for (int p = 0; p < 256; ++p) s += part[(size_t)p*4096 + i];
  yi[i] = s;
}

// ---- K7: per-(t,b,j) delta dot-products ----
template<bool F32> __device__ void delta_body(const float* H, const u16* wt, const void* st0,
                                              const int* pos, const void* done,
                                              const int* prev, const float* coef, float* dlt,
                                              float* diff){
  int n = blockIdx.x;
  int b = n & 31;
  int p = pos[n*2]*16 + pos[n*2+1];
  float m = 1.f - ld<F32>(done, n);
  int pv = prev[n];
  float cf = coef[n]*m;
  const float* hc = H + (size_t)n*MAPD;
  for (int c = threadIdx.x; c < MAPD; c += 128){
    float old;
    if (pv >= 0) old = H[(size_t)(pv*32 + b)*MAPD + c];
    else         old = ld<F32>(st0, ((size_t)b*MAPD + c)*256 + p);
    diff[c] = hc[c] - cf*old;
  }
  __syncthreads();
  int j = threadIdx.x;
  float acc = 0.f;
  for (int c = 0; c < MAPD; ++c)
    acc += diff[c]*bfv(wt[((size_t)p*MAPD + c)*128 + j]);
  dlt[(size_t)n*128 + j] = acc;
}
__global__ __launch_bounds__(128) void k_delta(const float* H, const u16* wt, const void* st0,
                                               const int* pos, const void* done,
                                               const int* prev, const float* coef, float* dlt,
                                               const int* flag){
  __shared__ float diff[MAPD];
  if (*flag) delta_body<true>(H,wt,st0,pos,done,prev,coef,dlt,diff);
  else       delta_body<false>(H,wt,st0,pos,done,prev,coef,dlt,diff);
}

// ---- K8: 32-step scan + head matvecs ----
template<bool F32> __device__ void scan_body(const float* yi, const float* dlt, const void* done,
                                             const void* pb1, const void* vb1,
                                             const void* pw2, const void* pb2,
                                             const void* vw2, const void* vb2, void* out,
                                             float* th){
  int b = blockIdx.x, j = threadIdx.x;
  float y = yi[b*128 + j];
  float bias = (j < 64) ? ld<F32>(pb1, j) : ld<F32>(vb1, j-64);
  for (int t = 0; t < T_; ++t){
    int n = t*32 + b;
    float m = 1.f - ld<F32>(done, n);
    y = m*y + dlt[(size_t)n*128 + j];
    th[j] = tanhf(y + bias);
    __syncthreads();
    if (j < 5){
      float s = ld<F32>(pb2, j);
      for (int q = 0; q < 64; ++q) s += th[q]*ld<F32>(pw2, j*64 + q);
      if constexpr (F32) ((float*)out)[n*5 + j] = s; else ((u16*)out)[n*5 + j] = fbf(s);
    } else if (j == 5){
      float s = ld<F32>(vb2, 0);
      for (int q = 0; q < 64; ++q) s += th[64 + q]*ld<F32>(vw2, q);
      if constexpr (F32) ((float*)out)[5120 + n] = s; else ((u16*)out)[5120 + n] = fbf(s);
    }
    __syncthreads();
  }
}
__global__ __launch_bounds__(128) void k_scan(const float* yi, const float* dlt, const void* done,
                                              const void* pb1, const void* vb1,
                                              const void* pw2, const void* pb2,
                                              const void* vw2, const void* vb2, void* out,
                                              const int* flag){
  __shared__ float th[128];
  if (*flag) scan_body<true>(yi,dlt,done,pb1,vb1,pw2,pb2,vw2,vb2,out,th);
  else       scan_body<false>(yi,dlt,done,pb1,vb1,pw2,pb2,vw2,vb2,out,th);
}

// ---- K9: final_state closed form ----
template<bool F32> __device__ void final_body(const float* H, const void* st0,
                                              const int* lastw, const float* lastc, void* out){
  size_t i = (size_t)blockIdx.x*256 + threadIdx.x;
  if (i >= (size_t)B_*FLATD) return;
  int b = (int)(i / FLATD);
  int r = (int)(i - (size_t)b*FLATD);
  int c = r >> 8, p = r & 255;
  int lw = lastw[b*256 + p];
  float lc = lastc[b*256 + p];
  float v;
  if (lw >= 0) v = H[(size_t)(lw*32 + b)*MAPD + c]*lc;
  else         v = ld<F32>(st0, i)*lc;
  if constexpr (F32) ((float*)out)[6144 + i] = v; else ((u16*)out)[6144 + i] = fbf(v);
}
__global__ __launch_bounds__(256) void k_final(const float* H, const void* st0,
                                               const int* lastw, const float* lastc, void* out,
                                               const int* flag){
  if (*flag) final_body<true>(H,st0,lastw,lastc,out); else final_body<false>(H,st0,lastw,lastc,out);
}

extern "C" void kernel_launch(void* const* d_in, const int* in_sizes, int n_in,
                              void* d_out, int out_size, void* d_ws, size_t ws_size,
                              hipStream_t stream) {
  (void)in_sizes; (void)n_in; (void)out_size; (void)ws_size;
  const void* image = d_in[0];
  const int*  lact  = (const int*)d_in[1];
  const int*  pos   = (const int*)d_in[2];
  const void* done  = d_in[3];
  const void* st0   = d_in[4];
  const void* c1w = d_in[5];  const void* c1b = d_in[6];
  const void* c2w = d_in[7];  const void* c2b = d_in[8];
  const void* c3w = d_in[9];  const void* c3b = d_in[10];
  const void* fcw = d_in[11]; const void* fcb = d_in[12];
  const void* pw1 = d_in[13]; const void* pb1 = d_in[14];
  const void* pw2 = d_in[15]; const void* pb2 = d_in[16];
  const void* vw1 = d_in[17]; const void* vb1 = d_in[18];
  const void* vw2 = d_in[19]; const void* vb2 = d_in[20];
  char* ws = (char*)d_ws;

  // workspace (~42 MB). WT overlays A/Bv/C (dead after fc).
  u16*   WT    = (u16*)  (ws + 0);           // 256*517*128*2 = 33,882,112
  u16*   A     = (u16*)  (ws + 0);           // 1024*7200*2
  u16*   Bv    = (u16*)  (ws + 14745600);    // 1024*2304*2
  u16*   C     = (u16*)  (ws + 19464192);    // 1024*1024*2
  float* H     = (float*)(ws + 33882368);    // 1024*517*4
  float* PART  = (float*)(ws + 36000256);    // 256*32*128*4
  float* YI    = (float*)(ws + 40194560);
  float* DLT   = (float*)(ws + 40210944);
  int*   PREV  = (int*)  (ws + 40735232);
  float* COEF  = (float*)(ws + 40739328);
  int*   LASTW = (int*)  (ws + 40743424);
  float* LASTC = (float*)(ws + 40776192);
  int*   FLAG  = (int*)  (ws + 40808960);
  u16*   W1T   = (u16*)  (ws + 40809216);    // 12,288 B
  u16*   W2T   = (u16*)  (ws + 40821504);    // 65,536 B
  u16*   W3T   = (u16*)  (ws + 40887040);    // 73,728 B
  u16*   FWT   = (u16*)  (ws + 40960768);    // 1,048,576 B

  k_probe<<<1, 64, 0, stream>>>(image, FLAG);
  k_wprep<<<2344, 256, 0, stream>>>(c1w, c2w, c3w, fcw, W1T, W2T, W3T, FWT, FLAG);
  k_prev <<<4, 256, 0, stream>>>(pos, done, lact, PREV, COEF, H, FLAG);
  k_last <<<32, 256, 0, stream>>>(pos, done, LASTW, LASTC, FLAG);
  k_conv1<<<1024, 256, 0, stream>>>(image, W1T, c1b, A, FLAG);
  k_conv2<<<1024, 256, 0, stream>>>(A, W2T, c2b, Bv, FLAG);
  k_conv3<<<1024, 256, 0, stream>>>(Bv, W3T, c3b, C, FLAG);
  k_fc   <<<256, 256, 0, stream>>>(C, FWT, fcb, H, FLAG);
  k_wt   <<<1034, 256, 0, stream>>>(pw1, vw1, WT, FLAG);
  k_yinit<<<512, 128, 0, stream>>>(st0, WT, PART, FLAG);
  k_yred <<<16, 256, 0, stream>>>(PART, YI);
  k_delta<<<1024, 128, 0, stream>>>(H, WT, st0, pos, done, PREV, COEF, DLT, FLAG);
  k_scan <<<32, 128, 0, stream>>>(YI, DLT, done, pb1, vb1, pw2, pb2, vw2, vb2, d_out, FLAG);
  k_final<<<16544, 256, 0, stream>>>(H, st0, LASTW, LASTC, d_out, FLAG);
}

// Round 4
// 692.811 us; speedup vs baseline: 1.3252x; 1.1328x over previous
//
#include <hip/hip_runtime.h>

#define T_ 32
#define B_ 32
#define MAPD 517
#define P_ 256
#define FLATD (MAPD*P_)   // 132352
#define TBN (T_*B_)       // 1024

typedef unsigned short u16;
typedef unsigned int u32;
typedef __attribute__((ext_vector_type(4))) short short4v;
typedef __attribute__((ext_vector_type(8))) short short8v;
typedef __attribute__((ext_vector_type(4))) float f32x4;

__device__ __forceinline__ float bfv(u16 u){ u32 x = ((u32)u)<<16; return __uint_as_float(x); }
__device__ __forceinline__ u16 fbf(float f){
  u32 x = __float_as_uint(f);
  return (u16)((x + 0x7fffu + ((x>>16)&1u))>>16);
}
template<bool F32> __device__ __forceinline__ float ld(const void* p, size_t i){
  if constexpr (F32) return ((const float*)p)[i];
  else               return bfv(((const u16*)p)[i]);
}

// ---- dtype probe: 1 if float inputs are fp32, 0 if bf16 ----
__global__ void k_probe(const void* img, int* flag){
  if (threadIdx.x == 0 && blockIdx.x == 0){
    const u16* u = (const u16*)img;
    int cnt = 0;
    for (int i = 0; i < 256; ++i) if (u[i] <= 0x4380u) ++cnt;
    *flag = (cnt < 240) ? 1 : 0;
  }
}

// ---- weight prep ----
// W1F: conv1 B-fragment layout: W1F[((nt*6+s)*64+l)*8+j] = c1w[oc*192 + kk],
//      oc = nt*16 + (l&15), kk = 8*(4s + (l>>4)) + j   (k-order = (c,ky,kx))
// W2T[k*64+oc]=c2w[oc*512+k]; W3T[k*64+oc]=c3w[oc*576+k];
// FWT[kk*512+o]=fcw[o*1024 + (kk&63)*16 + (kk>>6)]
__global__ void k_wprep(const void* c1w, const void* c2w, const void* c3w, const void* fcw,
                        u16* W1F, u16* W2T, u16* W3T, u16* FWT, const int* flag){
  bool f32 = (*flag != 0);
  int bid = blockIdx.x;
  if (bid < 24){
    int idx = bid*256 + threadIdx.x;           // 6144
    int j = idx & 7, l = (idx>>3) & 63, t = idx>>9;   // t = nt*6+s
    int nt = t/6, s = t - nt*6;
    int oc = nt*16 + (l&15);
    int kk = 8*(4*s + (l>>4)) + j;
    float v = f32 ? ((const float*)c1w)[oc*192+kk] : bfv(((const u16*)c1w)[oc*192+kk]);
    W1F[idx] = fbf(v);
  } else if (bid < 24+128){
    int idx = (bid-24)*256 + threadIdx.x;      // 32768
    int k = idx >> 6, oc = idx & 63;
    float v = f32 ? ((const float*)c2w)[oc*512+k] : bfv(((const u16*)c2w)[oc*512+k]);
    W2T[idx] = fbf(v);
  } else if (bid < 24+128+144){
    int idx = (bid-152)*256 + threadIdx.x;     // 36864
    int k = idx >> 6, oc = idx & 63;
    float v = f32 ? ((const float*)c3w)[oc*576+k] : bfv(((const u16*)c3w)[oc*576+k]);
    W3T[idx] = fbf(v);
  } else {
    int idx = (bid-296)*256 + threadIdx.x;     // 524288
    int kk = idx >> 9, o = idx & 511;
    int k = (kk & 63)*16 + (kk >> 6);
    float v = f32 ? ((const float*)fcw)[o*1024+k] : bfv(((const u16*)fcw)[o*1024+k]);
    FWT[idx] = fbf(v);
  }
}

// ---- st0 transpose: ST0T[p][c][b] bf16, coalesced both sides ----
__global__ __launch_bounds__(256) void k_st0t(const void* st0, u16* ST0T, const int* flag){
  __shared__ u16 tile[16384];   // [ci 8][pl 64][b 32]
  bool f32 = (*flag != 0);
  int c0 = (blockIdx.x >> 2)*8, p0 = (blockIdx.x & 3)*64;
  int tid = threadIdx.x;
  for (int it = 0; it < 64; ++it){
    int idx = it*256 + tid;
    int pl = idx & 63, b = (idx>>6)&31, ci = idx>>11;
    int c = c0 + ci;
    float v = 0.f;
    if (c < MAPD)
      v = f32 ? ((const float*)st0)[((size_t)b*MAPD+c)*256 + p0+pl]
              : bfv(((const u16*)st0)[((size_t)b*MAPD+c)*256 + p0+pl]);
    tile[ci*2048 + pl*32 + b] = fbf(v);
  }
  __syncthreads();
  for (int it = 0; it < 64; ++it){
    int idx = it*256 + tid;
    int b = idx & 31, ci = (idx>>5)&7, pl = idx>>8;
    int c = c0 + ci;
    if (c < MAPD)
      ST0T[((size_t)(p0+pl)*MAPD + c)*32 + b] = tile[ci*2048 + pl*32 + b];
  }
}

// ---- K5a: previous writer + mask coefficient + one-hot into H ----
template<bool F32> __device__ void prev_body(const int* pos, const void* done, const int* lact,
                                             int* prev, float* coef, float* H){
  int i = blockIdx.x*blockDim.x + threadIdx.x;
  if (i >= TBN) return;
  int t = i >> 5, b = i & 31;
  int p = pos[i*2]*16 + pos[i*2+1];
  int pv = -1;
  for (int s = t-1; s >= 0; --s){
    int n = s*32 + b;
    if (pos[n*2]*16 + pos[n*2+1] == p){ pv = s; break; }
  }
  float cf = 1.f;
  for (int s = (pv<0?0:pv+1); s <= t-1; ++s) cf *= (1.f - ld<F32>(done, s*32+b));
  prev[i] = pv; coef[i] = cf;
  int la = lact[i];
  #pragma unroll
  for (int a = 0; a < 5; ++a) H[(size_t)i*MAPD + 512 + a] = (la == a) ? 1.f : 0.f;
}
__global__ void k_prev(const int* pos, const void* done, const int* lact,
                       int* prev, float* coef, float* H, const int* flag){
  if (*flag) prev_body<true>(pos,done,lact,prev,coef,H); else prev_body<false>(pos,done,lact,prev,coef,H);
}

// ---- K5b: last writer of each (b,p) ----
template<bool F32> __device__ void last_body(const int* pos, const void* done, int* lastw, float* lastc){
  int i = blockIdx.x*blockDim.x + threadIdx.x;
  if (i >= B_*P_) return;
  int b = i >> 8, p = i & 255;
  int lw = -1;
  for (int s = T_-1; s >= 0; --s){
    int n = s*32 + b;
    if (pos[n*2]*16 + pos[n*2+1] == p){ lw = s; break; }
  }
  float cf = 1.f;
  for (int s = (lw<0?0:lw+1); s < T_; ++s) cf *= (1.f - ld<F32>(done, s*32+b));
  lastw[i] = lw; lastc[i] = cf;
}
__global__ void k_last(const int* pos, const void* done, int* lastw, float* lastc, const int* flag){
  if (*flag) last_body<true>(pos,done,lastw,lastc); else last_body<false>(pos,done,lastw,lastc);
}

// ---- K1: conv1 via MFMA implicit GEMM. M=225 pos (16 tiles), N=32 oc (2 tiles), K=192 (6 steps)
//      out[n][pos][oc] bf16 ----
__global__ __launch_bounds__(256) void k_conv1(const void* img, const u16* W1F, const void* bias,
                                               u16* out, const int* flag){
  __shared__ u16 sImg[12288];   // [c][y][x] bf16, 24 KB
  __shared__ u16 sWF[6144];     // B-frag layout, 12 KB
  __shared__ float sB[32];
  bool f32 = (*flag != 0);
  int n = blockIdx.x, tid = threadIdx.x;
  if (f32){
    const float4* ip = (const float4*)((const float*)img + (size_t)n*12288);
    for (int i = tid; i < 3072; i += 256){
      float4 v = ip[i];
      ushort4 u; u.x = fbf(v.x); u.y = fbf(v.y); u.z = fbf(v.z); u.w = fbf(v.w);
      *(ushort4*)(sImg + i*4) = u;
    }
  } else {
    const ushort4* ip = (const ushort4*)((const u16*)img + (size_t)n*12288);
    for (int i = tid; i < 3072; i += 256) *(ushort4*)(sImg + i*4) = ip[i];
  }
  { const ushort4* wf = (const ushort4*)W1F;
    for (int i = tid; i < 1536; i += 256) *(ushort4*)(sWF + i*4) = wf[i]; }
  if (tid < 32) sB[tid] = f32 ? ((const float*)bias)[tid] : bfv(((const u16*)bias)[tid]);
  __syncthreads();

  int wv = tid >> 6, lane = tid & 63;
  int mi = lane & 15, q = lane >> 4;

  short8v bfr[2][6];
  #pragma unroll
  for (int nt = 0; nt < 2; ++nt)
    #pragma unroll
    for (int s = 0; s < 6; ++s)
      bfr[nt][s] = *(const short8v*)(sWF + ((nt*6+s)*64 + lane)*8);   // 16B-aligned

  f32x4 acc[4][2];
  #pragma unroll
  for (int mt = 0; mt < 4; ++mt)
    #pragma unroll
    for (int nt = 0; nt < 2; ++nt)
      acc[mt][nt] = (f32x4){0.f,0.f,0.f,0.f};

  int base[4];
  #pragma unroll
  for (int mt = 0; mt < 4; ++mt){
    int m = (wv*4+mt)*16 + mi;
    int mc = m < 225 ? m : 224;       // clamp: keeps LDS in-bounds, results discarded
    int oy = mc/15, ox = mc - oy*15;
    base[mt] = oy*256 + ox*4;         // (4*oy)*64 + 4*ox
  }

  for (int s = 0; s < 6; ++s){
    int cky = 4*s + q;
    int off = (cky >> 3)*4096 + (cky & 7)*64;
    #pragma unroll
    for (int mt = 0; mt < 4; ++mt){
      const u16* ap = sImg + base[mt] + off;
      short4v lo = *(const short4v*)ap;        // 8B-aligned
      short4v hi = *(const short4v*)(ap + 4);
      short8v a = __builtin_shufflevector(lo, hi, 0,1,2,3,4,5,6,7);
      acc[mt][0] = __builtin_amdgcn_mfma_f32_16x16x32_bf16(a, bfr[0][s], acc[mt][0], 0,0,0);
      acc[mt][1] = __builtin_amdgcn_mfma_f32_16x16x32_bf16(a, bfr[1][s], acc[mt][1], 0,0,0);
    }
  }

  u16* ob = out + (size_t)n*7200;
  #pragma unroll
  for (int mt = 0; mt < 4; ++mt){
    int mrow0 = (wv*4+mt)*16 + q*4;   // D: row = quad*4 + reg
    #pragma unroll
    for (int nt = 0; nt < 2; ++nt){
      int oc = nt*16 + mi;            // D: col = lane&15
      float bv = sB[oc];
      #pragma unroll
      for (int r = 0; r < 4; ++r){
        int m = mrow0 + r;
        if (m < 225) ob[m*32 + oc] = fbf(fmaxf(acc[mt][nt][r] + bv, 0.f));
      }
    }
  }
}

// ---- K2: conv2 32x15x15 -> 64ch x 6x6, k4 s2, ReLU. in[n][pos][c], out[n][pos][oc] ----
template<bool F32> __device__ void conv2_body(const u16* A, const u16* w2t, const void* bias,
                                              u16* out, float* sIn, u16* sW){
  int n = blockIdx.x, tid = threadIdx.x;
  const u16* ip = A + (size_t)n*7200;
  for (int idx = tid; idx < 7200; idx += 256){
    int p = idx >> 5, c = idx & 31;
    int iy = p/15, ix = p - iy*15;
    sIn[(c*15+iy)*16 + ix] = bfv(ip[idx]);
  }
  int oc = tid & 63, pg = tid >> 6;
  int oyA[9], oxA[9];
  #pragma unroll
  for (int q = 0; q < 9; ++q){ int pq = pg*9+q; oyA[q] = pq/6; oxA[q] = pq - oyA[q]*6; }
  float acc[9];
  float bv = ld<F32>(bias, oc);
  #pragma unroll
  for (int q = 0; q < 9; ++q) acc[q] = bv;

  const ushort4* wsrc = (const ushort4*)w2t;
  for (int ch = 0; ch < 4; ++ch){
    __syncthreads();
    ushort4* swp = (ushort4*)sW;
    for (int i = tid; i < 2048; i += 256) swp[i] = wsrc[ch*2048 + i];
    __syncthreads();
    for (int c = 0; c < 8; ++c){
      float wv[16];
      #pragma unroll
      for (int j = 0; j < 16; ++j) wv[j] = bfv(sW[(c*16+j)*64 + oc]);
      int cg = (ch*8 + c)*15;
      #pragma unroll
      for (int ky = 0; ky < 4; ++ky){
        #pragma unroll
        for (int q = 0; q < 9; ++q){
          const float* rw = sIn + (cg + oyA[q]*2 + ky)*16 + oxA[q]*2;
          acc[q] += rw[0]*wv[ky*4+0] + rw[1]*wv[ky*4+1] + rw[2]*wv[ky*4+2] + rw[3]*wv[ky*4+3];
        }
      }
    }
  }
  u16* ob = out + (size_t)n*2304;
  #pragma unroll
  for (int q = 0; q < 9; ++q)
    ob[(pg*9+q)*64 + oc] = fbf(fmaxf(acc[q], 0.f));
}
__global__ __launch_bounds__(256) void k_conv2(const u16* A, const u16* w2t, const void* bias,
                                               u16* out, const int* flag){
  __shared__ float sIn[32*15*16];
  __shared__ u16   sW[8*16*64];
  if (*flag) conv2_body<true>(A,w2t,bias,out,sIn,sW);
  else       conv2_body<false>(A,w2t,bias,out,sIn,sW);
}

// ---- K3: conv3 64x6x6 -> 64ch x 4x4, k3 s1, ReLU ----
template<bool F32> __device__ void conv3_body(const u16* Bv, const u16* w3t, const void* bias,
                                              u16* out, float* sIn, u16* sW){
  int n = blockIdx.x, tid = threadIdx.x;
  const u16* ip = Bv + (size_t)n*2304;
  for (int idx = tid; idx < 2304; idx += 256){
    int p = idx >> 6, c = idx & 63;
    int iy = p/6, ix = p - iy*6;
    sIn[(c*6+iy)*8 + ix] = bfv(ip[idx]);
  }
  int oc = tid & 63, pg = tid >> 6;
  float acc[4];
  float bv = ld<F32>(bias, oc);
  #pragma unroll
  for (int q = 0; q < 4; ++q) acc[q] = bv;

  const ushort4* wsrc = (const ushort4*)w3t;
  for (int ch = 0; ch < 4; ++ch){
    __syncthreads();
    ushort4* swp = (ushort4*)sW;
    for (int i = tid; i < 2304; i += 256) swp[i] = wsrc[ch*2304 + i];
    __syncthreads();
    for (int c = 0; c < 16; ++c){
      float wv[9];
      #pragma unroll
      for (int j = 0; j < 9; ++j) wv[j] = bfv(sW[(c*9+j)*64 + oc]);
      int cc = ch*16 + c;
      #pragma unroll
      for (int ky = 0; ky < 3; ++ky){
        const float4* rp = (const float4*)(sIn + (cc*6 + pg + ky)*8);
        float4 r0 = rp[0], r1 = rp[1];
        float rr[8] = {r0.x,r0.y,r0.z,r0.w,r1.x,r1.y,r1.z,r1.w};
        #pragma unroll
        for (int q = 0; q < 4; ++q)
          acc[q] += rr[q]*wv[ky*3+0] + rr[q+1]*wv[ky*3+1] + rr[q+2]*wv[ky*3+2];
      }
    }
  }
  u16* ob = out + (size_t)n*1024;
  #pragma unroll
  for (int q = 0; q < 4; ++q)
    ob[(pg*4+q)*64 + oc] = fbf(fmaxf(acc[q], 0.f));
}
__global__ __launch_bounds__(256) void k_conv3(const u16* Bv, const u16* w3t, const void* bias,
                                               u16* out, const int* flag){
  __shared__ float sIn[64*6*8];
  __shared__ u16   sW[16*9*64];
  if (*flag) conv3_body<true>(Bv,w3t,bias,out,sIn,sW);
  else       conv3_body<false>(Bv,w3t,bias,out,sIn,sW);
}

// ---- K4: fc GEMM 1024x512x1024 + ReLU -> H[samp][517] fp32 ----
template<bool F32> __device__ void fc_body(const u16* C, const u16* FWT, const void* fb,
                                           float* H, u16* sA, u16* sB){
  int tid = threadIdx.x;
  int s0 = (blockIdx.x >> 3)*32, o0 = (blockIdx.x & 7)*64;
  int si = tid & 15, ojg = tid >> 4;
  float acc[2][4];
  #pragma unroll
  for (int a = 0; a < 2; ++a)
    #pragma unroll
    for (int j = 0; j < 4; ++j) acc[a][j] = 0.f;

  for (int kc = 0; kc < 8; ++kc){
    __syncthreads();
    for (int it = 0; it < 16; ++it){
      int idx = it*256 + tid;
      int s = idx >> 7, kk = idx & 127;
      sA[kk*34 + s] = C[(size_t)(s0+s)*1024 + kc*128 + kk];
    }
    for (int it = 0; it < 32; ++it){
      int idx = it*256 + tid;
      int kk = idx >> 6, oj = idx & 63;
      sB[kk*64 + oj] = FWT[(size_t)(kc*128+kk)*512 + o0 + oj];
    }
    __syncthreads();
    for (int k = 0; k < 128; ++k){
      ushort2 a2 = *(const ushort2*)(sA + k*34 + si*2);
      ushort4 b4 = *(const ushort4*)(sB + k*64 + ojg*4);
      float a0 = bfv(a2.x), a1 = bfv(a2.y);
      float b0 = bfv(b4.x), b1 = bfv(b4.y), b2 = bfv(b4.z), b3 = bfv(b4.w);
      acc[0][0] += a0*b0; acc[0][1] += a0*b1; acc[0][2] += a0*b2; acc[0][3] += a0*b3;
      acc[1][0] += a1*b0; acc[1][1] += a1*b1; acc[1][2] += a1*b2; acc[1][3] += a1*b3;
    }
  }
  #pragma unroll
  for (int ss = 0; ss < 2; ++ss)
    #pragma unroll
    for (int j = 0; j < 4; ++j){
      int o = o0 + ojg*4 + j;
      H[(size_t)(s0 + si*2 + ss)*MAPD + o] = fmaxf(acc[ss][j] + ld<F32>(fb, o), 0.f);
    }
}
__global__ __launch_bounds__(256) void k_fc(const u16* C, const u16* FWT, const void* fb,
                                            float* H, const int* flag){
  __shared__ u16 sA[128*34];
  __shared__ u16 sB[128*64];
  if (*flag) fc_body<true>(C,FWT,fb,H,sA,sB); else fc_body<false>(C,FWT,fb,H,sA,sB);
}

// ---- K0: transpose w1 (128 x 132352) into WT[p][c][j] bf16 ----
template<bool F32> __device__ void wt_body(const void* pw1, const void* vw1, u16* wt, u16* tile){
  int c  = blockIdx.x >> 1;
  int ph = blockIdx.x & 1;
  for (int idx = threadIdx.x; idx < 16384; idx += 256){
    int j = idx >> 7, pp = idx & 127;
    const void* w = (j < 64) ? pw1 : vw1;
    int jj = (j < 64) ? j : j - 64;
    tile[pp*129 + j] = fbf(ld<F32>(w, (size_t)jj*FLATD + c*P_ + ph*128 + pp));
  }
  __syncthreads();
  for (int idx = threadIdx.x; idx < 16384; idx += 256){
    int pp = idx >> 7, j = idx & 127;
    int p = ph*128 + pp;
    wt[((size_t)p*MAPD + c)*128 + j] = tile[pp*129 + j];
  }
}
__global__ __launch_bounds__(256) void k_wt(const void* pw1, const void* vw1, u16* wt, const int* flag){
  __shared__ u16 tile[128*129];
  if (*flag) wt_body<true>(pw1,vw1,wt,tile); else wt_body<false>(pw1,vw1,wt,tile);
}

// ---- K6: y_init partials: state0 . w1 per p-cell (reads coalesced ST0T) ----
__global__ __launch_bounds__(128) void k_yinit(const u16* __restrict__ ST0T, const u16* __restrict__ wt,
                                               float* __restrict__ part){
  __shared__ float s0[MAPD*16];
  int p  = blockIdx.x >> 1;
  int bh = blockIdx.x & 1;
  for (int idx = threadIdx.x; idx < MAPD*16; idx += 128){
    int c = idx >> 4, i = idx & 15;
    s0[c*16+i] = bfv(ST0T[((size_t)p*MAPD + c)*32 + bh*16 + i]);
  }
  __syncthreads();
  int j = threadIdx.x;
  float acc[16];
  #pragma unroll
  for (int i = 0; i < 16; ++i) acc[i] = 0.f;
  for (int c = 0; c < MAPD; ++c){
    float w = bfv(wt[((size_t)p*MAPD + c)*128 + j]);
    const float4* s4 = (const float4*)(s0 + c*16);
    float4 v0 = s4[0], v1 = s4[1], v2 = s4[2], v3 = s4[3];
    acc[0] += v0.x*w; acc[1] += v0.y*w; acc[2] += v0.z*w; acc[3] += v0.w*w;
    acc[4] += v1.x*w; acc[5] += v1.y*w; acc[6] += v1.z*w; acc[7] += v1.w*w;
    acc[8] += v2.x*w; acc[9] += v2.y*w; acc[10] += v2.z*w; acc[11] += v2.w*w;
    acc[12] += v3.x*w; acc[13] += v3.y*w; acc[14] += v3.z*w; acc[15] += v3.w*w;
  }
  #pragma unroll
  for (int i = 0; i < 16; ++i)
    part[((size_t)p*32 + bh*16 + i)*128 + j] = acc[i];
}

__global__ void k_yred(const float* __restrict__ part, float* __restrict__ yi){
  int i = blockIdx.x*blockDim.x + threadIdx.x;
  if (i >= 4096) return;
  float s = 0.f;
  for (int p = 0; p < 256; ++p) s += part[(size_t)p*4096 + i];
  yi[i] = s;
}

// ---- K7: per-(t,b,j) delta dot-products (state0 fallback via ST0T) ----
template<bool F32> __device__ void delta_body(const float* H, const u16* wt, const u16* st0t,
                                              const int* pos, const void* done,
                                              const int* prev, const float* coef, float* dlt,
                                              float* diff){
  int n = blockIdx.x;
  int b = n & 31;
  int p = pos[n*2]*16 + pos[n*2+1];
  float m = 1.f - ld<F32>(done, n);
  int pv = prev[n];
  float cf = coef[n]*m;
  const float* hc = H + (size_t)n*MAPD;
  for (int c = threadIdx.x; c < MAPD; c += 128){
    float old;
    if (pv >= 0) old = H[(size_t)(pv*32 + b)*MAPD + c];
    else         old = bfv(st0t[((size_t)p*MAPD + c)*32 + b]);
    diff[c] = hc[c] - cf*old;
  }
  __syncthreads();
  int j = threadIdx.x;
  float acc = 0.f;
  for (int c = 0; c < MAPD; ++c)
    acc += diff[c]*bfv(wt[((size_t)p*MAPD + c)*128 + j]);
  dlt[(size_t)n*128 + j] = acc;
}
__global__ __launch_bounds__(128) void k_delta(const float* H, const u16* wt, const u16* st0t,
                                               const int* pos, const void* done,
                                               const int* prev, const float* coef, float* dlt,
                                               const int* flag){
  __shared__ float diff[MAPD];
  if (*flag) delta_body<true>(H,wt,st0t,pos,done,prev,coef,dlt,diff);
  else       delta_body<false>(H,wt,st0t,pos,done,prev,coef,dlt,diff);
}

// ---- K8: 32-step scan + head matvecs ----
template<bool F32> __device__ void scan_body(const float* yi, const float* dlt, const void* done,
                                             const void* pb1, const void* vb1,
                                             const void* pw2, const void* pb2,
                                             const void* vw2, const void* vb2, void* out,
                                             float* th){
  int b = blockIdx.x, j = threadIdx.x;
  float y = yi[b*128 + j];
  float bias = (j < 64) ? ld<F32>(pb1, j) : ld<F32>(vb1, j-64);
  for (int t = 0; t < T_; ++t){
    int n = t*32 + b;
    float m = 1.f - ld<F32>(done, n);
    y = m*y + dlt[(size_t)n*128 + j];
    th[j] = tanhf(y + bias);
    __syncthreads();
    if (j < 5){
      float s = ld<F32>(pb2, j);
      for (int q = 0; q < 64; ++q) s += th[q]*ld<F32>(pw2, j*64 + q);
      if constexpr (F32) ((float*)out)[n*5 + j] = s; else ((u16*)out)[n*5 + j] = fbf(s);
    } else if (j == 5){
      float s = ld<F32>(vb2, 0);
      for (int q = 0; q < 64; ++q) s += th[64 + q]*ld<F32>(vw2, q);
      if constexpr (F32) ((float*)out)[5120 + n] = s; else ((u16*)out)[5120 + n] = fbf(s);
    }
    __syncthreads();
  }
}
__global__ __launch_bounds__(128) void k_scan(const float* yi, const float* dlt, const void* done,
                                              const void* pb1, const void* vb1,
                                              const void* pw2, const void* pb2,
                                              const void* vw2, const void* vb2, void* out,
                                              const int* flag){
  __shared__ float th[128];
  if (*flag) scan_body<true>(yi,dlt,done,pb1,vb1,pw2,pb2,vw2,vb2,out,th);
  else       scan_body<false>(yi,dlt,done,pb1,vb1,pw2,pb2,vw2,vb2,out,th);
}

// ---- K9: final_state closed form ----
template<bool F32> __device__ void final_body(const float* H, const void* st0,
                                              const int* lastw, const float* lastc, void* out){
  size_t i = (size_t)blockIdx.x*256 + threadIdx.x;
  if (i >= (size_t)B_*FLATD) return;
  int b = (int)(i / FLATD);
  int r = (int)(i - (size_t)b*FLATD);
  int c = r >> 8, p = r & 255;
  int lw = lastw[b*256 + p];
  float lc = lastc[b*256 + p];
  float v;
  if (lw >= 0) v = H[(size_t)(lw*32 + b)*MAPD + c]*lc;
  else         v = ld<F32>(st0, i)*lc;
  if constexpr (F32) ((float*)out)[6144 + i] = v; else ((u16*)out)[6144 + i] = fbf(v);
}
__global__ __launch_bounds__(256) void k_final(const float* H, const void* st0,
                                               const int* lastw, const float* lastc, void* out,
                                               const int* flag){
  if (*flag) final_body<true>(H,st0,lastw,lastc,out); else final_body<false>(H,st0,lastw,lastc,out);
}

extern "C" void kernel_launch(void* const* d_in, const int* in_sizes, int n_in,
                              void* d_out, int out_size, void* d_ws, size_t ws_size,
                              hipStream_t stream) {
  (void)in_sizes; (void)n_in; (void)out_size; (void)ws_size;
  const void* image = d_in[0];
  const int*  lact  = (const int*)d_in[1];
  const int*  pos   = (const int*)d_in[2];
  const void* done  = d_in[3];
  const void* st0   = d_in[4];
  const void* c1w = d_in[5];  const void* c1b = d_in[6];
  const void* c2w = d_in[7];  const void* c2b = d_in[8];
  const void* c3w = d_in[9];  const void* c3b = d_in[10];
  const void* fcw = d_in[11]; const void* fcb = d_in[12];
  const void* pw1 = d_in[13]; const void* pb1 = d_in[14];
  const void* pw2 = d_in[15]; const void* pb2 = d_in[16];
  const void* vw1 = d_in[17]; const void* vb1 = d_in[18];
  const void* vw2 = d_in[19]; const void* vb2 = d_in[20];
  char* ws = (char*)d_ws;

  // workspace (~50.5 MB). WT overlays A/Bv/C (dead after fc).
  u16*   WT    = (u16*)  (ws + 0);           // 256*517*128*2 = 33,882,112
  u16*   A     = (u16*)  (ws + 0);           // 1024*7200*2
  u16*   Bv    = (u16*)  (ws + 14745600);    // 1024*2304*2
  u16*   C     = (u16*)  (ws + 19464192);    // 1024*1024*2
  float* H     = (float*)(ws + 33882368);    // 1024*517*4
  float* PART  = (float*)(ws + 36000256);    // 256*32*128*4
  float* YI    = (float*)(ws + 40194560);
  float* DLT   = (float*)(ws + 40210944);
  int*   PREV  = (int*)  (ws + 40735232);
  float* COEF  = (float*)(ws + 40739328);
  int*   LASTW = (int*)  (ws + 40743424);
  float* LASTC = (float*)(ws + 40776192);
  int*   FLAG  = (int*)  (ws + 40808960);
  u16*   W1F   = (u16*)  (ws + 40809216);    // 12,288 B (conv1 B-frag layout)
  u16*   W2T   = (u16*)  (ws + 40821504);    // 65,536 B
  u16*   W3T   = (u16*)  (ws + 40887040);    // 73,728 B
  u16*   FWT   = (u16*)  (ws + 40960768);    // 1,048,576 B
  u16*   ST0T  = (u16*)  (ws + 42009600);    // 256*517*32*2 = 8,470,528 B

  k_probe<<<1, 64, 0, stream>>>(image, FLAG);
  k_wprep<<<2344, 256, 0, stream>>>(c1w, c2w, c3w, fcw, W1F, W2T, W3T, FWT, FLAG);
  k_st0t <<<260, 256, 0, stream>>>(st0, ST0T, FLAG);
  k_prev <<<4, 256, 0, stream>>>(pos, done, lact, PREV, COEF, H, FLAG);
  k_last <<<32, 256, 0, stream>>>(pos, done, LASTW, LASTC, FLAG);
  k_conv1<<<1024, 256, 0, stream>>>(image, W1F, c1b, A, FLAG);
  k_conv2<<<1024, 256, 0, stream>>>(A, W2T, c2b, Bv, FLAG);
  k_conv3<<<1024, 256, 0, stream>>>(Bv, W3T, c3b, C, FLAG);
  k_fc   <<<256, 256, 0, stream>>>(C, FWT, fcb, H, FLAG);
  k_wt   <<<1034, 256, 0, stream>>>(pw1, vw1, WT, FLAG);
  k_yinit<<<512, 128, 0, stream>>>(ST0T, WT, PART);
  k_yred <<<16, 256, 0, stream>>>(PART, YI);
  k_delta<<<1024, 128, 0, stream>>>(H, WT, ST0T, pos, done, PREV, COEF, DLT, FLAG);
  k_scan <<<32, 128, 0, stream>>>(YI, DLT, done, pb1, vb1, pw2, pb2, vw2, vb2, d_out, FLAG);
  k_final<<<16544, 256, 0, stream>>>(H, st0, LASTW, LASTC, d_out, FLAG);
}

// Round 5
// 551.147 us; speedup vs baseline: 1.6658x; 1.2570x over previous
//
#include <hip/hip_runtime.h>

#define T_ 32
#define B_ 32
#define MAPD 517
#define P_ 256
#define FLATD (MAPD*P_)   // 132352
#define TBN (T_*B_)       // 1024

typedef unsigned short u16;
typedef unsigned int u32;
typedef __attribute__((ext_vector_type(4))) short short4v;
typedef __attribute__((ext_vector_type(8))) short short8v;
typedef __attribute__((ext_vector_type(4))) float f32x4;

__device__ __forceinline__ float bfv(u16 u){ u32 x = ((u32)u)<<16; return __uint_as_float(x); }
__device__ __forceinline__ u16 fbf(float f){
  u32 x = __float_as_uint(f);
  return (u16)((x + 0x7fffu + ((x>>16)&1u))>>16);
}
template<bool F32> __device__ __forceinline__ float ld(const void* p, size_t i){
  if constexpr (F32) return ((const float*)p)[i];
  else               return bfv(((const u16*)p)[i]);
}

// ---- dtype probe: 1 if float inputs are fp32, 0 if bf16 ----
__global__ void k_probe(const void* img, int* flag){
  if (threadIdx.x == 0 && blockIdx.x == 0){
    const u16* u = (const u16*)img;
    int cnt = 0;
    for (int i = 0; i < 256; ++i) if (u[i] <= 0x4380u) ++cnt;
    *flag = (cnt < 240) ? 1 : 0;
  }
}

// ---- weight prep ----
// W1F (conv1 B-frag): W1F[((nt*6+s)*64+l)*8+j] = c1w[oc*192+kk], oc=nt*16+(l&15), kk=8*(4s+(l>>4))+j
// W2F (conv2 B-frag): idx=nt*8192+s*512+l*8+j -> c2w[oc*512 + cin*16 + (s>>2)*4 + (s&3)],
//                     oc=nt*16+(l&15), cin=(l>>4)*8+j      (k-order: (ky,kx,cin), s=ky*4+kx)
// W3F (conv3 B-frag): idx=nt*9216+s*512+l*8+j -> c3w[oc*576 + c*9 + pair],
//                     oc=nt*16+(l&15), c=(s&1)*32+(l>>4)*8+j, pair=s>>1  (k-order: (ky,kx,c))
// FWT[kk*512+o]=fcw[o*1024 + (kk&63)*16 + (kk>>6)]
__global__ void k_wprep(const void* c1w, const void* c2w, const void* c3w, const void* fcw,
                        u16* W1F, u16* W2F, u16* W3F, u16* FWT, const int* flag){
  bool f32 = (*flag != 0);
  int bid = blockIdx.x;
  if (bid < 24){
    int idx = bid*256 + threadIdx.x;           // 6144
    int j = idx & 7, l = (idx>>3) & 63, t = idx>>9;
    int nt = t/6, s = t - nt*6;
    int oc = nt*16 + (l&15);
    int kk = 8*(4*s + (l>>4)) + j;
    float v = f32 ? ((const float*)c1w)[oc*192+kk] : bfv(((const u16*)c1w)[oc*192+kk]);
    W1F[idx] = fbf(v);
  } else if (bid < 24+128){
    int idx = (bid-24)*256 + threadIdx.x;      // 32768
    int j = idx & 7, l = (idx>>3) & 63, s = (idx>>9) & 15, nt = idx>>13;
    int oc = nt*16 + (l&15);
    int cin = (l>>4)*8 + j;
    int src = oc*512 + cin*16 + (s>>2)*4 + (s&3);
    float v = f32 ? ((const float*)c2w)[src] : bfv(((const u16*)c2w)[src]);
    W2F[idx] = fbf(v);
  } else if (bid < 24+128+144){
    int idx = (bid-152)*256 + threadIdx.x;     // 36864
    int j = idx & 7, l = (idx>>3) & 63, t = idx>>9;   // t = nt*18+s
    int nt = t/18, s = t - nt*18;
    int oc = nt*16 + (l&15);
    int c = (s&1)*32 + (l>>4)*8 + j;
    int src = oc*576 + c*9 + (s>>1);
    float v = f32 ? ((const float*)c3w)[src] : bfv(((const u16*)c3w)[src]);
    W3F[idx] = fbf(v);
  } else {
    int idx = (bid-296)*256 + threadIdx.x;     // 524288
    int kk = idx >> 9, o = idx & 511;
    int k = (kk & 63)*16 + (kk >> 6);
    float v = f32 ? ((const float*)fcw)[o*1024+k] : bfv(((const u16*)fcw)[o*1024+k]);
    FWT[idx] = fbf(v);
  }
}

// ---- st0 transpose: ST0T[p][c][b] bf16 ----
__global__ __launch_bounds__(256) void k_st0t(const void* st0, u16* ST0T, const int* flag){
  __shared__ u16 tile[16384];
  bool f32 = (*flag != 0);
  int c0 = (blockIdx.x >> 2)*8, p0 = (blockIdx.x & 3)*64;
  int tid = threadIdx.x;
  for (int it = 0; it < 64; ++it){
    int idx = it*256 + tid;
    int pl = idx & 63, b = (idx>>6)&31, ci = idx>>11;
    int c = c0 + ci;
    float v = 0.f;
    if (c < MAPD)
      v = f32 ? ((const float*)st0)[((size_t)b*MAPD+c)*256 + p0+pl]
              : bfv(((const u16*)st0)[((size_t)b*MAPD+c)*256 + p0+pl]);
    tile[ci*2048 + pl*32 + b] = fbf(v);
  }
  __syncthreads();
  for (int it = 0; it < 64; ++it){
    int idx = it*256 + tid;
    int b = idx & 31, ci = (idx>>5)&7, pl = idx>>8;
    int c = c0 + ci;
    if (c < MAPD)
      ST0T[((size_t)(p0+pl)*MAPD + c)*32 + b] = tile[ci*2048 + pl*32 + b];
  }
}

// ---- K5a: previous writer + mask coefficient + one-hot into H ----
template<bool F32> __device__ void prev_body(const int* pos, const void* done, const int* lact,
                                             int* prev, float* coef, float* H){
  int i = blockIdx.x*blockDim.x + threadIdx.x;
  if (i >= TBN) return;
  int t = i >> 5, b = i & 31;
  int p = pos[i*2]*16 + pos[i*2+1];
  int pv = -1;
  for (int s = t-1; s >= 0; --s){
    int n = s*32 + b;
    if (pos[n*2]*16 + pos[n*2+1] == p){ pv = s; break; }
  }
  float cf = 1.f;
  for (int s = (pv<0?0:pv+1); s <= t-1; ++s) cf *= (1.f - ld<F32>(done, s*32+b));
  prev[i] = pv; coef[i] = cf;
  int la = lact[i];
  #pragma unroll
  for (int a = 0; a < 5; ++a) H[(size_t)i*MAPD + 512 + a] = (la == a) ? 1.f : 0.f;
}
__global__ void k_prev(const int* pos, const void* done, const int* lact,
                       int* prev, float* coef, float* H, const int* flag){
  if (*flag) prev_body<true>(pos,done,lact,prev,coef,H); else prev_body<false>(pos,done,lact,prev,coef,H);
}

// ---- K5b: last writer of each (b,p) ----
template<bool F32> __device__ void last_body(const int* pos, const void* done, int* lastw, float* lastc){
  int i = blockIdx.x*blockDim.x + threadIdx.x;
  if (i >= B_*P_) return;
  int b = i >> 8, p = i & 255;
  int lw = -1;
  for (int s = T_-1; s >= 0; --s){
    int n = s*32 + b;
    if (pos[n*2]*16 + pos[n*2+1] == p){ lw = s; break; }
  }
  float cf = 1.f;
  for (int s = (lw<0?0:lw+1); s < T_; ++s) cf *= (1.f - ld<F32>(done, s*32+b));
  lastw[i] = lw; lastc[i] = cf;
}
__global__ void k_last(const int* pos, const void* done, int* lastw, float* lastc, const int* flag){
  if (*flag) last_body<true>(pos,done,lastw,lastc); else last_body<false>(pos,done,lastw,lastc);
}

// ---- K1: conv1 MFMA implicit GEMM. M=225 (16 tiles), N=32 (2 tiles), K=192 (6 steps) ----
__global__ __launch_bounds__(256) void k_conv1(const void* img, const u16* W1F, const void* bias,
                                               u16* out, const int* flag){
  __shared__ u16 sImg[12288];
  __shared__ u16 sWF[6144];
  __shared__ float sB[32];
  bool f32 = (*flag != 0);
  int n = blockIdx.x, tid = threadIdx.x;
  if (f32){
    const float4* ip = (const float4*)((const float*)img + (size_t)n*12288);
    for (int i = tid; i < 3072; i += 256){
      float4 v = ip[i];
      ushort4 u; u.x = fbf(v.x); u.y = fbf(v.y); u.z = fbf(v.z); u.w = fbf(v.w);
      *(ushort4*)(sImg + i*4) = u;
    }
  } else {
    const ushort4* ip = (const ushort4*)((const u16*)img + (size_t)n*12288);
    for (int i = tid; i < 3072; i += 256) *(ushort4*)(sImg + i*4) = ip[i];
  }
  { const ushort4* wf = (const ushort4*)W1F;
    for (int i = tid; i < 1536; i += 256) *(ushort4*)(sWF + i*4) = wf[i]; }
  if (tid < 32) sB[tid] = f32 ? ((const float*)bias)[tid] : bfv(((const u16*)bias)[tid]);
  __syncthreads();

  int wv = tid >> 6, lane = tid & 63;
  int mi = lane & 15, q = lane >> 4;

  short8v bfr[2][6];
  #pragma unroll
  for (int nt = 0; nt < 2; ++nt)
    #pragma unroll
    for (int s = 0; s < 6; ++s)
      bfr[nt][s] = *(const short8v*)(sWF + ((nt*6+s)*64 + lane)*8);

  f32x4 acc[4][2];
  #pragma unroll
  for (int mt = 0; mt < 4; ++mt)
    #pragma unroll
    for (int nt = 0; nt < 2; ++nt)
      acc[mt][nt] = (f32x4){0.f,0.f,0.f,0.f};

  int base[4];
  #pragma unroll
  for (int mt = 0; mt < 4; ++mt){
    int m = (wv*4+mt)*16 + mi;
    int mc = m < 225 ? m : 224;
    int oy = mc/15, ox = mc - oy*15;
    base[mt] = oy*256 + ox*4;
  }

  for (int s = 0; s < 6; ++s){
    int cky = 4*s + q;
    int off = (cky >> 3)*4096 + (cky & 7)*64;
    #pragma unroll
    for (int mt = 0; mt < 4; ++mt){
      const u16* ap = sImg + base[mt] + off;
      short4v lo = *(const short4v*)ap;
      short4v hi = *(const short4v*)(ap + 4);
      short8v a = __builtin_shufflevector(lo, hi, 0,1,2,3,4,5,6,7);
      acc[mt][0] = __builtin_amdgcn_mfma_f32_16x16x32_bf16(a, bfr[0][s], acc[mt][0], 0,0,0);
      acc[mt][1] = __builtin_amdgcn_mfma_f32_16x16x32_bf16(a, bfr[1][s], acc[mt][1], 0,0,0);
    }
  }

  u16* ob = out + (size_t)n*7200;
  #pragma unroll
  for (int mt = 0; mt < 4; ++mt){
    int mrow0 = (wv*4+mt)*16 + q*4;
    #pragma unroll
    for (int nt = 0; nt < 2; ++nt){
      int oc = nt*16 + mi;
      float bv = sB[oc];
      #pragma unroll
      for (int r = 0; r < 4; ++r){
        int m = mrow0 + r;
        if (m < 225) ob[m*32 + oc] = fbf(fmaxf(acc[mt][nt][r] + bv, 0.f));
      }
    }
  }
}

// ---- K2: conv2 MFMA implicit GEMM. M=36 (3 tiles), N=64 (4 waves x 1 tile), K=512 (16 steps)
//      in [n][pos 225][c 32], out [n][pos 36][oc 64] ----
__global__ __launch_bounds__(256) void k_conv2(const u16* __restrict__ A, const u16* __restrict__ W2F,
                                               const void* bias, u16* __restrict__ out, const int* flag){
  __shared__ u16 sIn[7200];
  bool f32 = (*flag != 0);
  int n = blockIdx.x, tid = threadIdx.x;
  const ushort4* ip = (const ushort4*)(A + (size_t)n*7200);
  for (int i = tid; i < 1800; i += 256) *(ushort4*)(sIn + i*4) = ip[i];
  int wv = tid >> 6, lane = tid & 63, mi = lane & 15, q = lane >> 4;

  short8v bfr[16];
  #pragma unroll
  for (int s = 0; s < 16; ++s)
    bfr[s] = ((const short8v*)W2F)[(wv*16+s)*64 + lane];   // coalesced, L2-resident

  int oc = wv*16 + mi;
  float bv = f32 ? ((const float*)bias)[oc] : bfv(((const u16*)bias)[oc]);
  f32x4 acc[3];
  #pragma unroll
  for (int mt = 0; mt < 3; ++mt) acc[mt] = (f32x4){0.f,0.f,0.f,0.f};
  int base[3];
  #pragma unroll
  for (int mt = 0; mt < 3; ++mt){
    int m = mt*16 + mi; if (m > 35) m = 35;
    int oy = m/6, ox = m - oy*6;
    base[mt] = (oy*30 + ox*2)*32;          // ((oy*2)*15 + ox*2)*32
  }
  __syncthreads();
  #pragma unroll
  for (int s = 0; s < 16; ++s){
    int off = ((s>>2)*15 + (s&3))*32 + q*8;   // (ky*15+kx)*32 + q*8 ; 16B aligned
    #pragma unroll
    for (int mt = 0; mt < 3; ++mt){
      short8v a = *(const short8v*)(sIn + base[mt] + off);
      acc[mt] = __builtin_amdgcn_mfma_f32_16x16x32_bf16(a, bfr[s], acc[mt], 0,0,0);
    }
  }
  u16* ob = out + (size_t)n*2304;
  #pragma unroll
  for (int mt = 0; mt < 3; ++mt)
    #pragma unroll
    for (int r = 0; r < 4; ++r){
      int m = mt*16 + q*4 + r;
      if (m < 36) ob[m*64 + oc] = fbf(fmaxf(acc[mt][r] + bv, 0.f));
    }
}

// ---- K3: conv3 MFMA implicit GEMM. M=16 (1 tile), N=64 (4 waves), K=576 (18 steps)
//      in [n][pos 36][c 64], out [n][pos 16][oc 64] ----
__global__ __launch_bounds__(256) void k_conv3(const u16* __restrict__ Bv, const u16* __restrict__ W3F,
                                               const void* bias, u16* __restrict__ out, const int* flag){
  __shared__ u16 sIn[2304];
  bool f32 = (*flag != 0);
  int n = blockIdx.x, tid = threadIdx.x;
  const ushort4* ip = (const ushort4*)(Bv + (size_t)n*2304);
  for (int i = tid; i < 576; i += 256) *(ushort4*)(sIn + i*4) = ip[i];
  int wv = tid >> 6, lane = tid & 63, mi = lane & 15, q = lane >> 4;
  int oy = mi >> 2, ox = mi & 3;
  int oc = wv*16 + mi;
  float bv = f32 ? ((const float*)bias)[oc] : bfv(((const u16*)bias)[oc]);

  short8v bfr[18];
  #pragma unroll
  for (int s = 0; s < 18; ++s)
    bfr[s] = ((const short8v*)W3F)[(wv*18+s)*64 + lane];

  f32x4 acc = (f32x4){0.f,0.f,0.f,0.f};
  __syncthreads();
  #pragma unroll
  for (int s = 0; s < 18; ++s){
    int pair = s >> 1, ky = pair/3, kx = pair - ky*3;
    int off = ((oy+ky)*6 + ox+kx)*64 + (s&1)*32 + q*8;   // 16B aligned
    short8v a = *(const short8v*)(sIn + off);
    acc = __builtin_amdgcn_mfma_f32_16x16x32_bf16(a, bfr[s], acc, 0,0,0);
  }
  u16* ob = out + (size_t)n*1024;
  #pragma unroll
  for (int r = 0; r < 4; ++r)
    ob[(q*4+r)*64 + oc] = fbf(fmaxf(acc[r] + bv, 0.f));
}

// ---- K4: fc GEMM 1024x512x1024 + ReLU -> H[samp][517] fp32 ----
template<bool F32> __device__ void fc_body(const u16* C, const u16* FWT, const void* fb,
                                           float* H, u16* sA, u16* sB){
  int tid = threadIdx.x;
  int s0 = (blockIdx.x >> 3)*32, o0 = (blockIdx.x & 7)*64;
  int si = tid & 15, ojg = tid >> 4;
  float acc[2][4];
  #pragma unroll
  for (int a = 0; a < 2; ++a)
    #pragma unroll
    for (int j = 0; j < 4; ++j) acc[a][j] = 0.f;

  for (int kc = 0; kc < 8; ++kc){
    __syncthreads();
    for (int it = 0; it < 16; ++it){
      int idx = it*256 + tid;
      int s = idx >> 7, kk = idx & 127;
      sA[kk*34 + s] = C[(size_t)(s0+s)*1024 + kc*128 + kk];
    }
    for (int it = 0; it < 32; ++it){
      int idx = it*256 + tid;
      int kk = idx >> 6, oj = idx & 63;
      sB[kk*64 + oj] = FWT[(size_t)(kc*128+kk)*512 + o0 + oj];
    }
    __syncthreads();
    for (int k = 0; k < 128; ++k){
      ushort2 a2 = *(const ushort2*)(sA + k*34 + si*2);
      ushort4 b4 = *(const ushort4*)(sB + k*64 + ojg*4);
      float a0 = bfv(a2.x), a1 = bfv(a2.y);
      float b0 = bfv(b4.x), b1 = bfv(b4.y), b2 = bfv(b4.z), b3 = bfv(b4.w);
      acc[0][0] += a0*b0; acc[0][1] += a0*b1; acc[0][2] += a0*b2; acc[0][3] += a0*b3;
      acc[1][0] += a1*b0; acc[1][1] += a1*b1; acc[1][2] += a1*b2; acc[1][3] += a1*b3;
    }
  }
  #pragma unroll
  for (int ss = 0; ss < 2; ++ss)
    #pragma unroll
    for (int j = 0; j < 4; ++j){
      int o = o0 + ojg*4 + j;
      H[(size_t)(s0 + si*2 + ss)*MAPD + o] = fmaxf(acc[ss][j] + ld<F32>(fb, o), 0.f);
    }
}
__global__ __launch_bounds__(256) void k_fc(const u16* C, const u16* FWT, const void* fb,
                                            float* H, const int* flag){
  __shared__ u16 sA[128*34];
  __shared__ u16 sB[128*64];
  if (*flag) fc_body<true>(C,FWT,fb,H,sA,sB); else fc_body<false>(C,FWT,fb,H,sA,sB);
}

// ---- K0: transpose w1 (128 x 132352) into WT[p][c][j] bf16 ----
template<bool F32> __device__ void wt_body(const void* pw1, const void* vw1, u16* wt, u16* tile){
  int c  = blockIdx.x >> 1;
  int ph = blockIdx.x & 1;
  for (int idx = threadIdx.x; idx < 16384; idx += 256){
    int j = idx >> 7, pp = idx & 127;
    const void* w = (j < 64) ? pw1 : vw1;
    int jj = (j < 64) ? j : j - 64;
    tile[pp*129 + j] = fbf(ld<F32>(w, (size_t)jj*FLATD + c*P_ + ph*128 + pp));
  }
  __syncthreads();
  for (int idx = threadIdx.x; idx < 16384; idx += 256){
    int pp = idx >> 7, j = idx & 127;
    int p = ph*128 + pp;
    wt[((size_t)p*MAPD + c)*128 + j] = tile[pp*129 + j];
  }
}
__global__ __launch_bounds__(256) void k_wt(const void* pw1, const void* vw1, u16* wt, const int* flag){
  __shared__ u16 tile[128*129];
  if (*flag) wt_body<true>(pw1,vw1,wt,tile); else wt_body<false>(pw1,vw1,wt,tile);
}

// ---- K6: y_init partials ----
__global__ __launch_bounds__(128) void k_yinit(const u16* __restrict__ ST0T, const u16* __restrict__ wt,
                                               float* __restrict__ part){
  __shared__ float s0[MAPD*16];
  int p  = blockIdx.x >> 1;
  int bh = blockIdx.x & 1;
  for (int idx = threadIdx.x; idx < MAPD*16; idx += 128){
    int c = idx >> 4, i = idx & 15;
    s0[c*16+i] = bfv(ST0T[((size_t)p*MAPD + c)*32 + bh*16 + i]);
  }
  __syncthreads();
  int j = threadIdx.x;
  float acc[16];
  #pragma unroll
  for (int i = 0; i < 16; ++i) acc[i] = 0.f;
  for (int c = 0; c < MAPD; ++c){
    float w = bfv(wt[((size_t)p*MAPD + c)*128 + j]);
    const float4* s4 = (const float4*)(s0 + c*16);
    float4 v0 = s4[0], v1 = s4[1], v2 = s4[2], v3 = s4[3];
    acc[0] += v0.x*w; acc[1] += v0.y*w; acc[2] += v0.z*w; acc[3] += v0.w*w;
    acc[4] += v1.x*w; acc[5] += v1.y*w; acc[6] += v1.z*w; acc[7] += v1.w*w;
    acc[8] += v2.x*w; acc[9] += v2.y*w; acc[10] += v2.z*w; acc[11] += v2.w*w;
    acc[12] += v3.x*w; acc[13] += v3.y*w; acc[14] += v3.z*w; acc[15] += v3.w*w;
  }
  #pragma unroll
  for (int i = 0; i < 16; ++i)
    part[((size_t)p*32 + bh*16 + i)*128 + j] = acc[i];
}

__global__ void k_yred(const float* __restrict__ part, float* __restrict__ yi){
  int i = blockIdx.x*blockDim.x + threadIdx.x;
  if (i >= 4096) return;
  float s = 0.f;
  for (int p = 0; p < 256; ++p) s += part[(size_t)p*4096 + i];
  yi[i] = s;
}

// ---- K7: per-(t,b,j) delta dot-products ----
template<bool F32> __device__ void delta_body(const float* H, const u16* wt, const u16* st0t,
                                              const int* pos, const void* done,
                                              const int* prev, const float* coef, float* dlt,
                                              float* diff){
  int n = blockIdx.x;
  int b = n & 31;
  int p = pos[n*2]*16 + pos[n*2+1];
  float m = 1.f - ld<F32>(done, n);
  int pv = prev[n];
  float cf = coef[n]*m;
  const float* hc = H + (size_t)n*MAPD;
  for (int c = threadIdx.x; c < MAPD; c += 128){
    float old;
    if (pv >= 0) old = H[(size_t)(pv*32 + b)*MAPD + c];
    else         old = bfv(st0t[((size_t)p*MAPD + c)*32 + b]);
    diff[c] = hc[c] - cf*old;
  }
  __syncthreads();
  int j = threadIdx.x;
  float acc = 0.f;
  for (int c = 0; c < MAPD; ++c)
    acc += diff[c]*bfv(wt[((size_t)p*MAPD + c)*128 + j]);
  dlt[(size_t)n*128 + j] = acc;
}
__global__ __launch_bounds__(128) void k_delta(const float* H, const u16* wt, const u16* st0t,
                                               const int* pos, const void* done,
                                               const int* prev, const float* coef, float* dlt,
                                               const int* flag){
  __shared__ float diff[MAPD];
  if (*flag) delta_body<true>(H,wt,st0t,pos,done,prev,coef,dlt,diff);
  else       delta_body<false>(H,wt,st0t,pos,done,prev,coef,dlt,diff);
}

// ---- K8: 32-step scan + head matvecs ----
template<bool F32> __device__ void scan_body(const float* yi, const float* dlt, const void* done,
                                             const void* pb1, const void* vb1,
                                             const void* pw2, const void* pb2,
                                             const void* vw2, const void* vb2, void* out,
                                             float* th){
  int b = blockIdx.x, j = threadIdx.x;
  float y = yi[b*128 + j];
  float bias = (j < 64) ? ld<F32>(pb1, j) : ld<F32>(vb1, j-64);
  for (int t = 0; t < T_; ++t){
    int n = t*32 + b;
    float m = 1.f - ld<F32>(done, n);
    y = m*y + dlt[(size_t)n*128 + j];
    th[j] = tanhf(y + bias);
    __syncthreads();
    if (j < 5){
      float s = ld<F32>(pb2, j);
      for (int q = 0; q < 64; ++q) s += th[q]*ld<F32>(pw2, j*64 + q);
      if constexpr (F32) ((float*)out)[n*5 + j] = s; else ((u16*)out)[n*5 + j] = fbf(s);
    } else if (j == 5){
      float s = ld<F32>(vb2, 0);
      for (int q = 0; q < 64; ++q) s += th[64 + q]*ld<F32>(vw2, q);
      if constexpr (F32) ((float*)out)[5120 + n] = s; else ((u16*)out)[5120 + n] = fbf(s);
    }
    __syncthreads();
  }
}
__global__ __launch_bounds__(128) void k_scan(const float* yi, const float* dlt, const void* done,
                                              const void* pb1, const void* vb1,
                                              const void* pw2, const void* pb2,
                                              const void* vw2, const void* vb2, void* out,
                                              const int* flag){
  __shared__ float th[128];
  if (*flag) scan_body<true>(yi,dlt,done,pb1,vb1,pw2,pb2,vw2,vb2,out,th);
  else       scan_body<false>(yi,dlt,done,pb1,vb1,pw2,pb2,vw2,vb2,out,th);
}

// ---- K9: final_state closed form ----
template<bool F32> __device__ void final_body(const float* H, const void* st0,
                                              const int* lastw, const float* lastc, void* out){
  size_t i = (size_t)blockIdx.x*256 + threadIdx.x;
  if (i >= (size_t)B_*FLATD) return;
  int b = (int)(i / FLATD);
  int r = (int)(i - (size_t)b*FLATD);
  int c = r >> 8, p = r & 255;
  int lw = lastw[b*256 + p];
  float lc = lastc[b*256 + p];
  float v;
  if (lw >= 0) v = H[(size_t)(lw*32 + b)*MAPD + c]*lc;
  else         v = ld<F32>(st0, i)*lc;
  if constexpr (F32) ((float*)out)[6144 + i] = v; else ((u16*)out)[6144 + i] = fbf(v);
}
__global__ __launch_bounds__(256) void k_final(const float* H, const void* st0,
                                               const int* lastw, const float* lastc, void* out,
                                               const int* flag){
  if (*flag) final_body<true>(H,st0,lastw,lastc,out); else final_body<false>(H,st0,lastw,lastc,out);
}

extern "C" void kernel_launch(void* const* d_in, const int* in_sizes, int n_in,
                              void* d_out, int out_size, void* d_ws, size_t ws_size,
                              hipStream_t stream) {
  (void)in_sizes; (void)n_in; (void)out_size; (void)ws_size;
  const void* image = d_in[0];
  const int*  lact  = (const int*)d_in[1];
  const int*  pos   = (const int*)d_in[2];
  const void* done  = d_in[3];
  const void* st0   = d_in[4];
  const void* c1w = d_in[5];  const void* c1b = d_in[6];
  const void* c2w = d_in[7];  const void* c2b = d_in[8];
  const void* c3w = d_in[9];  const void* c3b = d_in[10];
  const void* fcw = d_in[11]; const void* fcb = d_in[12];
  const void* pw1 = d_in[13]; const void* pb1 = d_in[14];
  const void* pw2 = d_in[15]; const void* pb2 = d_in[16];
  const void* vw1 = d_in[17]; const void* vb1 = d_in[18];
  const void* vw2 = d_in[19]; const void* vb2 = d_in[20];
  char* ws = (char*)d_ws;

  u16*   WT    = (u16*)  (ws + 0);           // 256*517*128*2 = 33,882,112
  u16*   A     = (u16*)  (ws + 0);           // overlays WT (dead after fc)
  u16*   Bv    = (u16*)  (ws + 14745600);
  u16*   C     = (u16*)  (ws + 19464192);
  float* H     = (float*)(ws + 33882368);
  float* PART  = (float*)(ws + 36000256);
  float* YI    = (float*)(ws + 40194560);
  float* DLT   = (float*)(ws + 40210944);
  int*   PREV  = (int*)  (ws + 40735232);
  float* COEF  = (float*)(ws + 40739328);
  int*   LASTW = (int*)  (ws + 40743424);
  float* LASTC = (float*)(ws + 40776192);
  int*   FLAG  = (int*)  (ws + 40808960);
  u16*   W1F   = (u16*)  (ws + 40809216);    // 12,288 B
  u16*   W2F   = (u16*)  (ws + 40821504);    // 65,536 B
  u16*   W3F   = (u16*)  (ws + 40887040);    // 73,728 B
  u16*   FWT   = (u16*)  (ws + 40960768);    // 1,048,576 B
  u16*   ST0T  = (u16*)  (ws + 42009600);    // 8,470,528 B

  k_probe<<<1, 64, 0, stream>>>(image, FLAG);
  k_wprep<<<2344, 256, 0, stream>>>(c1w, c2w, c3w, fcw, W1F, W2F, W3F, FWT, FLAG);
  k_st0t <<<260, 256, 0, stream>>>(st0, ST0T, FLAG);
  k_prev <<<4, 256, 0, stream>>>(pos, done, lact, PREV, COEF, H, FLAG);
  k_last <<<32, 256, 0, stream>>>(pos, done, LASTW, LASTC, FLAG);
  k_conv1<<<1024, 256, 0, stream>>>(image, W1F, c1b, A, FLAG);
  k_conv2<<<1024, 256, 0, stream>>>(A, W2F, c2b, Bv, FLAG);
  k_conv3<<<1024, 256, 0, stream>>>(Bv, W3F, c3b, C, FLAG);
  k_fc   <<<256, 256, 0, stream>>>(C, FWT, fcb, H, FLAG);
  k_wt   <<<1034, 256, 0, stream>>>(pw1, vw1, WT, FLAG);
  k_yinit<<<512, 128, 0, stream>>>(ST0T, WT, PART);
  k_yred <<<16, 256, 0, stream>>>(PART, YI);
  k_delta<<<1024, 128, 0, stream>>>(H, WT, ST0T, pos, done, PREV, COEF, DLT, FLAG);
  k_scan <<<32, 128, 0, stream>>>(YI, DLT, done, pb1, vb1, pw2, pb2, vw2, vb2, d_out, FLAG);
  k_final<<<16544, 256, 0, stream>>>(H, st0, LASTW, LASTC, d_out, FLAG);
}

// Round 6
// 496.656 us; speedup vs baseline: 1.8486x; 1.1097x over previous
//
#include <hip/hip_runtime.h>

#define T_ 32
#define B_ 32
#define MAPD 517
#define P_ 256
#define FLATD (MAPD*P_)   // 132352
#define TBN (T_*B_)       // 1024

typedef unsigned short u16;
typedef unsigned int u32;
typedef __attribute__((ext_vector_type(4))) short short4v;
typedef __attribute__((ext_vector_type(8))) short short8v;
typedef __attribute__((ext_vector_type(4))) float f32x4;

__device__ __forceinline__ float bfv(u16 u){ u32 x = ((u32)u)<<16; return __uint_as_float(x); }
__device__ __forceinline__ u16 fbf(float f){
  u32 x = __float_as_uint(f);
  return (u16)((x + 0x7fffu + ((x>>16)&1u))>>16);
}
template<bool F32> __device__ __forceinline__ float ld(const void* p, size_t i){
  if constexpr (F32) return ((const float*)p)[i];
  else               return bfv(((const u16*)p)[i]);
}

// ---- dtype probe: 1 if float inputs are fp32, 0 if bf16 ----
__global__ void k_probe(const void* img, int* flag){
  if (threadIdx.x == 0 && blockIdx.x == 0){
    const u16* u = (const u16*)img;
    int cnt = 0;
    for (int i = 0; i < 256; ++i) if (u[i] <= 0x4380u) ++cnt;
    *flag = (cnt < 240) ? 1 : 0;
  }
}

// ---- weight prep (conv frag layouts; FWT handled by k_fwt) ----
__global__ void k_wprep(const void* c1w, const void* c2w, const void* c3w,
                        u16* W1F, u16* W2F, u16* W3F, const int* flag){
  bool f32 = (*flag != 0);
  int bid = blockIdx.x;
  if (bid < 24){
    int idx = bid*256 + threadIdx.x;           // 6144
    int j = idx & 7, l = (idx>>3) & 63, t = idx>>9;
    int nt = t/6, s = t - nt*6;
    int oc = nt*16 + (l&15);
    int kk = 8*(4*s + (l>>4)) + j;
    float v = f32 ? ((const float*)c1w)[oc*192+kk] : bfv(((const u16*)c1w)[oc*192+kk]);
    W1F[idx] = fbf(v);
  } else if (bid < 24+128){
    int idx = (bid-24)*256 + threadIdx.x;      // 32768
    int j = idx & 7, l = (idx>>3) & 63, s = (idx>>9) & 15, nt = idx>>13;
    int oc = nt*16 + (l&15);
    int cin = (l>>4)*8 + j;
    int src = oc*512 + cin*16 + (s>>2)*4 + (s&3);
    float v = f32 ? ((const float*)c2w)[src] : bfv(((const u16*)c2w)[src]);
    W2F[idx] = fbf(v);
  } else {
    int idx = (bid-152)*256 + threadIdx.x;     // 36864
    int j = idx & 7, l = (idx>>3) & 63, t = idx>>9;   // t = nt*18+s
    int nt = t/18, s = t - nt*18;
    int oc = nt*16 + (l&15);
    int c = (s&1)*32 + (l>>4)*8 + j;
    int src = oc*576 + c*9 + (s>>1);
    float v = f32 ? ((const float*)c3w)[src] : bfv(((const u16*)c3w)[src]);
    W3F[idx] = fbf(v);
  }
}

// ---- FWT tiled transpose: FWT[kk*512+o] = fcw[o*1024+k], kk=(k&15)*64+(k>>4) ----
__global__ __launch_bounds__(256) void k_fwt(const void* fcw, u16* FWT, const int* flag){
  __shared__ float t[64*65];
  bool f32 = (*flag != 0);
  int o0 = (blockIdx.x >> 4)*64, k0 = (blockIdx.x & 15)*64;
  int tid = threadIdx.x;
  for (int it = 0; it < 16; ++it){
    int idx = it*256 + tid;
    int oo = idx >> 6, kk = idx & 63;
    float v = f32 ? ((const float*)fcw)[(size_t)(o0+oo)*1024 + k0+kk]
                  : bfv(((const u16*)fcw)[(size_t)(o0+oo)*1024 + k0+kk]);
    t[oo*65 + kk] = v;
  }
  __syncthreads();
  for (int it = 0; it < 16; ++it){
    int idx = it*256 + tid;
    int oo = idx & 63, dk = idx >> 6;
    int k = k0 + dk;
    int kk = (k & 15)*64 + (k >> 4);
    FWT[(size_t)kk*512 + o0 + oo] = fbf(t[oo*65 + dk]);
  }
}

// ---- st0 transpose: ST0T[p][c][b] bf16 ----
__global__ __launch_bounds__(256) void k_st0t(const void* st0, u16* ST0T, const int* flag){
  __shared__ u16 tile[16384];
  bool f32 = (*flag != 0);
  int c0 = (blockIdx.x >> 2)*8, p0 = (blockIdx.x & 3)*64;
  int tid = threadIdx.x;
  for (int it = 0; it < 64; ++it){
    int idx = it*256 + tid;
    int pl = idx & 63, b = (idx>>6)&31, ci = idx>>11;
    int c = c0 + ci;
    float v = 0.f;
    if (c < MAPD)
      v = f32 ? ((const float*)st0)[((size_t)b*MAPD+c)*256 + p0+pl]
              : bfv(((const u16*)st0)[((size_t)b*MAPD+c)*256 + p0+pl]);
    tile[ci*2048 + pl*32 + b] = fbf(v);
  }
  __syncthreads();
  for (int it = 0; it < 64; ++it){
    int idx = it*256 + tid;
    int b = idx & 31, ci = (idx>>5)&7, pl = idx>>8;
    int c = c0 + ci;
    if (c < MAPD)
      ST0T[((size_t)(p0+pl)*MAPD + c)*32 + b] = tile[ci*2048 + pl*32 + b];
  }
}

// ---- K5a: previous writer + mask coefficient + one-hot into H + zero YI ----
template<bool F32> __device__ void prev_body(const int* pos, const void* done, const int* lact,
                                             int* prev, float* coef, float* H, float* YI){
  int i = blockIdx.x*blockDim.x + threadIdx.x;
  if (i >= TBN) return;
  ((float4*)YI)[i] = (float4){0.f,0.f,0.f,0.f};   // YI = 4096 floats, zero before k_yinit atomics
  int t = i >> 5, b = i & 31;
  int p = pos[i*2]*16 + pos[i*2+1];
  int pv = -1;
  for (int s = t-1; s >= 0; --s){
    int n = s*32 + b;
    if (pos[n*2]*16 + pos[n*2+1] == p){ pv = s; break; }
  }
  float cf = 1.f;
  for (int s = (pv<0?0:pv+1); s <= t-1; ++s) cf *= (1.f - ld<F32>(done, s*32+b));
  prev[i] = pv; coef[i] = cf;
  int la = lact[i];
  #pragma unroll
  for (int a = 0; a < 5; ++a) H[(size_t)i*MAPD + 512 + a] = (la == a) ? 1.f : 0.f;
}
__global__ void k_prev(const int* pos, const void* done, const int* lact,
                       int* prev, float* coef, float* H, float* YI, const int* flag){
  if (*flag) prev_body<true>(pos,done,lact,prev,coef,H,YI);
  else       prev_body<false>(pos,done,lact,prev,coef,H,YI);
}

// ---- K5b: last writer of each (b,p) ----
template<bool F32> __device__ void last_body(const int* pos, const void* done, int* lastw, float* lastc){
  int i = blockIdx.x*blockDim.x + threadIdx.x;
  if (i >= B_*P_) return;
  int b = i >> 8, p = i & 255;
  int lw = -1;
  for (int s = T_-1; s >= 0; --s){
    int n = s*32 + b;
    if (pos[n*2]*16 + pos[n*2+1] == p){ lw = s; break; }
  }
  float cf = 1.f;
  for (int s = (lw<0?0:lw+1); s < T_; ++s) cf *= (1.f - ld<F32>(done, s*32+b));
  lastw[i] = lw; lastc[i] = cf;
}
__global__ void k_last(const int* pos, const void* done, int* lastw, float* lastc, const int* flag){
  if (*flag) last_body<true>(pos,done,lastw,lastc); else last_body<false>(pos,done,lastw,lastc);
}

// ---- K1: conv1 MFMA implicit GEMM. M=225 (16 tiles), N=32 (2 tiles), K=192 (6 steps) ----
__global__ __launch_bounds__(256) void k_conv1(const void* img, const u16* W1F, const void* bias,
                                               u16* out, const int* flag){
  __shared__ u16 sImg[12288];
  __shared__ u16 sWF[6144];
  __shared__ float sB[32];
  bool f32 = (*flag != 0);
  int n = blockIdx.x, tid = threadIdx.x;
  if (f32){
    const float4* ip = (const float4*)((const float*)img + (size_t)n*12288);
    for (int i = tid; i < 3072; i += 256){
      float4 v = ip[i];
      ushort4 u; u.x = fbf(v.x); u.y = fbf(v.y); u.z = fbf(v.z); u.w = fbf(v.w);
      *(ushort4*)(sImg + i*4) = u;
    }
  } else {
    const ushort4* ip = (const ushort4*)((const u16*)img + (size_t)n*12288);
    for (int i = tid; i < 3072; i += 256) *(ushort4*)(sImg + i*4) = ip[i];
  }
  { const ushort4* wf = (const ushort4*)W1F;
    for (int i = tid; i < 1536; i += 256) *(ushort4*)(sWF + i*4) = wf[i]; }
  if (tid < 32) sB[tid] = f32 ? ((const float*)bias)[tid] : bfv(((const u16*)bias)[tid]);
  __syncthreads();

  int wv = tid >> 6, lane = tid & 63;
  int mi = lane & 15, q = lane >> 4;

  short8v bfr[2][6];
  #pragma unroll
  for (int nt = 0; nt < 2; ++nt)
    #pragma unroll
    for (int s = 0; s < 6; ++s)
      bfr[nt][s] = *(const short8v*)(sWF + ((nt*6+s)*64 + lane)*8);

  f32x4 acc[4][2];
  #pragma unroll
  for (int mt = 0; mt < 4; ++mt)
    #pragma unroll
    for (int nt = 0; nt < 2; ++nt)
      acc[mt][nt] = (f32x4){0.f,0.f,0.f,0.f};

  int base[4];
  #pragma unroll
  for (int mt = 0; mt < 4; ++mt){
    int m = (wv*4+mt)*16 + mi;
    int mc = m < 225 ? m : 224;
    int oy = mc/15, ox = mc - oy*15;
    base[mt] = oy*256 + ox*4;
  }

  for (int s = 0; s < 6; ++s){
    int cky = 4*s + q;
    int off = (cky >> 3)*4096 + (cky & 7)*64;
    #pragma unroll
    for (int mt = 0; mt < 4; ++mt){
      const u16* ap = sImg + base[mt] + off;
      short4v lo = *(const short4v*)ap;
      short4v hi = *(const short4v*)(ap + 4);
      short8v a = __builtin_shufflevector(lo, hi, 0,1,2,3,4,5,6,7);
      acc[mt][0] = __builtin_amdgcn_mfma_f32_16x16x32_bf16(a, bfr[0][s], acc[mt][0], 0,0,0);
      acc[mt][1] = __builtin_amdgcn_mfma_f32_16x16x32_bf16(a, bfr[1][s], acc[mt][1], 0,0,0);
    }
  }

  u16* ob = out + (size_t)n*7200;
  #pragma unroll
  for (int mt = 0; mt < 4; ++mt){
    int mrow0 = (wv*4+mt)*16 + q*4;
    #pragma unroll
    for (int nt = 0; nt < 2; ++nt){
      int oc = nt*16 + mi;
      float bv = sB[oc];
      #pragma unroll
      for (int r = 0; r < 4; ++r){
        int m = mrow0 + r;
        if (m < 225) ob[m*32 + oc] = fbf(fmaxf(acc[mt][nt][r] + bv, 0.f));
      }
    }
  }
}

// ---- K2: conv2 MFMA implicit GEMM ----
__global__ __launch_bounds__(256) void k_conv2(const u16* __restrict__ A, const u16* __restrict__ W2F,
                                               const void* bias, u16* __restrict__ out, const int* flag){
  __shared__ u16 sIn[7200];
  bool f32 = (*flag != 0);
  int n = blockIdx.x, tid = threadIdx.x;
  const ushort4* ip = (const ushort4*)(A + (size_t)n*7200);
  for (int i = tid; i < 1800; i += 256) *(ushort4*)(sIn + i*4) = ip[i];
  int wv = tid >> 6, lane = tid & 63, mi = lane & 15, q = lane >> 4;

  short8v bfr[16];
  #pragma unroll
  for (int s = 0; s < 16; ++s)
    bfr[s] = ((const short8v*)W2F)[(wv*16+s)*64 + lane];

  int oc = wv*16 + mi;
  float bv = f32 ? ((const float*)bias)[oc] : bfv(((const u16*)bias)[oc]);
  f32x4 acc[3];
  #pragma unroll
  for (int mt = 0; mt < 3; ++mt) acc[mt] = (f32x4){0.f,0.f,0.f,0.f};
  int base[3];
  #pragma unroll
  for (int mt = 0; mt < 3; ++mt){
    int m = mt*16 + mi; if (m > 35) m = 35;
    int oy = m/6, ox = m - oy*6;
    base[mt] = (oy*30 + ox*2)*32;
  }
  __syncthreads();
  #pragma unroll
  for (int s = 0; s < 16; ++s){
    int off = ((s>>2)*15 + (s&3))*32 + q*8;
    #pragma unroll
    for (int mt = 0; mt < 3; ++mt){
      short8v a = *(const short8v*)(sIn + base[mt] + off);
      acc[mt] = __builtin_amdgcn_mfma_f32_16x16x32_bf16(a, bfr[s], acc[mt], 0,0,0);
    }
  }
  u16* ob = out + (size_t)n*2304;
  #pragma unroll
  for (int mt = 0; mt < 3; ++mt)
    #pragma unroll
    for (int r = 0; r < 4; ++r){
      int m = mt*16 + q*4 + r;
      if (m < 36) ob[m*64 + oc] = fbf(fmaxf(acc[mt][r] + bv, 0.f));
    }
}

// ---- K3: conv3 MFMA implicit GEMM ----
__global__ __launch_bounds__(256) void k_conv3(const u16* __restrict__ Bv, const u16* __restrict__ W3F,
                                               const void* bias, u16* __restrict__ out, const int* flag){
  __shared__ u16 sIn[2304];
  bool f32 = (*flag != 0);
  int n = blockIdx.x, tid = threadIdx.x;
  const ushort4* ip = (const ushort4*)(Bv + (size_t)n*2304);
  for (int i = tid; i < 576; i += 256) *(ushort4*)(sIn + i*4) = ip[i];
  int wv = tid >> 6, lane = tid & 63, mi = lane & 15, q = lane >> 4;
  int oy = mi >> 2, ox = mi & 3;
  int oc = wv*16 + mi;
  float bv = f32 ? ((const float*)bias)[oc] : bfv(((const u16*)bias)[oc]);

  short8v bfr[18];
  #pragma unroll
  for (int s = 0; s < 18; ++s)
    bfr[s] = ((const short8v*)W3F)[(wv*18+s)*64 + lane];

  f32x4 acc = (f32x4){0.f,0.f,0.f,0.f};
  __syncthreads();
  #pragma unroll
  for (int s = 0; s < 18; ++s){
    int pair = s >> 1, ky = pair/3, kx = pair - ky*3;
    int off = ((oy+ky)*6 + ox+kx)*64 + (s&1)*32 + q*8;
    short8v a = *(const short8v*)(sIn + off);
    acc = __builtin_amdgcn_mfma_f32_16x16x32_bf16(a, bfr[s], acc, 0,0,0);
  }
  u16* ob = out + (size_t)n*1024;
  #pragma unroll
  for (int r = 0; r < 4; ++r)
    ob[(q*4+r)*64 + oc] = fbf(fmaxf(acc[r] + bv, 0.f));
}

// ---- K4: fc GEMM 1024x512x1024 + ReLU -> H[samp][517] fp32 ----
template<bool F32> __device__ void fc_body(const u16* C, const u16* FWT, const void* fb,
                                           float* H, u16* sA, u16* sB){
  int tid = threadIdx.x;
  int s0 = (blockIdx.x >> 3)*32, o0 = (blockIdx.x & 7)*64;
  int si = tid & 15, ojg = tid >> 4;
  float acc[2][4];
  #pragma unroll
  for (int a = 0; a < 2; ++a)
    #pragma unroll
    for (int j = 0; j < 4; ++j) acc[a][j] = 0.f;

  for (int kc = 0; kc < 8; ++kc){
    __syncthreads();
    for (int it = 0; it < 16; ++it){
      int idx = it*256 + tid;
      int s = idx >> 7, kk = idx & 127;
      sA[kk*34 + s] = C[(size_t)(s0+s)*1024 + kc*128 + kk];
    }
    for (int it = 0; it < 32; ++it){
      int idx = it*256 + tid;
      int kk = idx >> 6, oj = idx & 63;
      sB[kk*64 + oj] = FWT[(size_t)(kc*128+kk)*512 + o0 + oj];
    }
    __syncthreads();
    for (int k = 0; k < 128; ++k){
      ushort2 a2 = *(const ushort2*)(sA + k*34 + si*2);
      ushort4 b4 = *(const ushort4*)(sB + k*64 + ojg*4);
      float a0 = bfv(a2.x), a1 = bfv(a2.y);
      float b0 = bfv(b4.x), b1 = bfv(b4.y), b2 = bfv(b4.z), b3 = bfv(b4.w);
      acc[0][0] += a0*b0; acc[0][1] += a0*b1; acc[0][2] += a0*b2; acc[0][3] += a0*b3;
      acc[1][0] += a1*b0; acc[1][1] += a1*b1; acc[1][2] += a1*b2; acc[1][3] += a1*b3;
    }
  }
  #pragma unroll
  for (int ss = 0; ss < 2; ++ss)
    #pragma unroll
    for (int j = 0; j < 4; ++j){
      int o = o0 + ojg*4 + j;
      H[(size_t)(s0 + si*2 + ss)*MAPD + o] = fmaxf(acc[ss][j] + ld<F32>(fb, o), 0.f);
    }
}
__global__ __launch_bounds__(256) void k_fc(const u16* C, const u16* FWT, const void* fb,
                                            float* H, const int* flag){
  __shared__ u16 sA[128*34];
  __shared__ u16 sB[128*64];
  if (*flag) fc_body<true>(C,FWT,fb,H,sA,sB); else fc_body<false>(C,FWT,fb,H,sA,sB);
}

// ---- K0: transpose w1 (128 x 132352) into WT[p][c][j] bf16 ----
template<bool F32> __device__ void wt_body(const void* pw1, const void* vw1, u16* wt, u16* tile){
  int c  = blockIdx.x >> 1;
  int ph = blockIdx.x & 1;
  for (int idx = threadIdx.x; idx < 16384; idx += 256){
    int j = idx >> 7, pp = idx & 127;
    const void* w = (j < 64) ? pw1 : vw1;
    int jj = (j < 64) ? j : j - 64;
    tile[pp*129 + j] = fbf(ld<F32>(w, (size_t)jj*FLATD + c*P_ + ph*128 + pp));
  }
  __syncthreads();
  for (int idx = threadIdx.x; idx < 16384; idx += 256){
    int pp = idx >> 7, j = idx & 127;
    int p = ph*128 + pp;
    wt[((size_t)p*MAPD + c)*128 + j] = tile[pp*129 + j];
  }
}
__global__ __launch_bounds__(256) void k_wt(const void* pw1, const void* vw1, u16* wt, const int* flag){
  __shared__ u16 tile[128*129];
  if (*flag) wt_body<true>(pw1,vw1,wt,tile); else wt_body<false>(pw1,vw1,wt,tile);
}

// ---- K6: y_init: YI[b][j] += st0[p-cell chunk] . wt ; grid (p x 4 c-chunks) ----
__global__ __launch_bounds__(256) void k_yinit(const u16* __restrict__ ST0T, const u16* __restrict__ wt,
                                               float* __restrict__ YI){
  __shared__ u16 sW[130*128];      // 33,280 B
  __shared__ float sS[130*32];     // 16,640 B
  int p = blockIdx.x >> 2, cq = blockIdx.x & 3;
  int c0 = cq*130;
  int clen = (cq == 3) ? 127 : 130;
  int tid = threadIdx.x;
  const ushort4* wsrc = (const ushort4*)(wt + ((size_t)p*MAPD + c0)*128);
  ushort4* wdst = (ushort4*)sW;
  int n4 = clen*32;
  for (int i = tid; i < n4; i += 256) wdst[i] = wsrc[i];
  const u16* ssrc = ST0T + ((size_t)p*MAPD + c0)*32;
  for (int i = tid; i < clen*32; i += 256) sS[i] = bfv(ssrc[i]);
  __syncthreads();

  int jg = tid & 63, bg = tid >> 6;   // wave = 64 jg, uniform bg -> s0 reads broadcast
  int j0 = jg*2, b0 = bg*8;
  float acc[8][2];
  #pragma unroll
  for (int bb = 0; bb < 8; ++bb){ acc[bb][0] = 0.f; acc[bb][1] = 0.f; }

  for (int c = 0; c < clen; ++c){
    u32 wp = *(const u32*)(sW + c*128 + j0);
    float w0 = bfv((u16)(wp & 0xffffu)), w1 = bfv((u16)(wp >> 16));
    const float4* s4 = (const float4*)(sS + c*32 + b0);
    float4 sa = s4[0], sb = s4[1];
    float sv[8] = {sa.x,sa.y,sa.z,sa.w,sb.x,sb.y,sb.z,sb.w};
    #pragma unroll
    for (int bb = 0; bb < 8; ++bb){
      acc[bb][0] += sv[bb]*w0;
      acc[bb][1] += sv[bb]*w1;
    }
  }
  #pragma unroll
  for (int bb = 0; bb < 8; ++bb){
    atomicAdd(&YI[(b0+bb)*128 + j0    ], acc[bb][0]);
    atomicAdd(&YI[(b0+bb)*128 + j0 + 1], acc[bb][1]);
  }
}

// ---- K7: delta partial dots; grid (n x 4 c-chunks) -> DLT4[n*4+cq][j] ----
__global__ __launch_bounds__(128) void k_delta(const float* __restrict__ H, const u16* __restrict__ wt,
                                               const u16* __restrict__ st0t,
                                               const int* __restrict__ pos, const void* done,
                                               const int* __restrict__ prev, const float* __restrict__ coef,
                                               float* __restrict__ dlt4, const int* flag){
  __shared__ float diff[132];
  bool f32 = (*flag != 0);
  int n = blockIdx.x >> 2, cq = blockIdx.x & 3;
  int c0 = cq*130, clen = (cq == 3) ? 127 : 130;
  int b = n & 31;
  int p = pos[n*2]*16 + pos[n*2+1];
  float dn = f32 ? ((const float*)done)[n] : bfv(((const u16*)done)[n]);
  float m = 1.f - dn;
  int pv = prev[n];
  float cf = coef[n]*m;
  const float* hc = H + (size_t)n*MAPD + c0;
  for (int c = threadIdx.x; c < clen; c += 128){
    float old;
    if (pv >= 0) old = H[(size_t)(pv*32 + b)*MAPD + c0 + c];
    else         old = bfv(st0t[((size_t)p*MAPD + c0 + c)*32 + b]);
    diff[c] = hc[c] - cf*old;
  }
  __syncthreads();
  int j = threadIdx.x;
  const u16* wp = wt + ((size_t)p*MAPD + c0)*128 + j;
  float acc = 0.f;
  int c = 0;
  for (; c + 4 <= clen; c += 4){
    u16 w0 = wp[(size_t)c*128], w1 = wp[(size_t)(c+1)*128];
    u16 w2 = wp[(size_t)(c+2)*128], w3 = wp[(size_t)(c+3)*128];
    acc += diff[c]*bfv(w0) + diff[c+1]*bfv(w1) + diff[c+2]*bfv(w2) + diff[c+3]*bfv(w3);
  }
  for (; c < clen; ++c) acc += diff[c]*bfv(wp[(size_t)c*128]);
  dlt4[(size_t)blockIdx.x*128 + j] = acc;
}

// ---- K8: 32-step scan + head matvecs (sums 4 delta partials) ----
template<bool F32> __device__ void scan_body(const float* yi, const float* dlt4, const void* done,
                                             const void* pb1, const void* vb1,
                                             const void* pw2, const void* pb2,
                                             const void* vw2, const void* vb2, void* out,
                                             float* th){
  int b = blockIdx.x, j = threadIdx.x;
  float y = yi[b*128 + j];
  float bias = (j < 64) ? ld<F32>(pb1, j) : ld<F32>(vb1, j-64);
  for (int t = 0; t < T_; ++t){
    int n = t*32 + b;
    float m = 1.f - ld<F32>(done, n);
    const float* dp = dlt4 + (size_t)n*4*128 + j;
    float d = dp[0] + dp[128] + dp[256] + dp[384];
    y = m*y + d;
    th[j] = tanhf(y + bias);
    __syncthreads();
    if (j < 5){
      float s = ld<F32>(pb2, j);
      for (int q = 0; q < 64; ++q) s += th[q]*ld<F32>(pw2, j*64 + q);
      if constexpr (F32) ((float*)out)[n*5 + j] = s; else ((u16*)out)[n*5 + j] = fbf(s);
    } else if (j == 5){
      float s = ld<F32>(vb2, 0);
      for (int q = 0; q < 64; ++q) s += th[64 + q]*ld<F32>(vw2, q);
      if constexpr (F32) ((float*)out)[5120 + n] = s; else ((u16*)out)[5120 + n] = fbf(s);
    }
    __syncthreads();
  }
}
__global__ __launch_bounds__(128) void k_scan(const float* yi, const float* dlt4, const void* done,
                                              const void* pb1, const void* vb1,
                                              const void* pw2, const void* pb2,
                                              const void* vw2, const void* vb2, void* out,
                                              const int* flag){
  __shared__ float th[128];
  if (*flag) scan_body<true>(yi,dlt4,done,pb1,vb1,pw2,pb2,vw2,vb2,out,th);
  else       scan_body<false>(yi,dlt4,done,pb1,vb1,pw2,pb2,vw2,vb2,out,th);
}

// ---- K9: final_state closed form ----
template<bool F32> __device__ void final_body(const float* H, const void* st0,
                                              const int* lastw, const float* lastc, void* out){
  size_t i = (size_t)blockIdx.x*256 + threadIdx.x;
  if (i >= (size_t)B_*FLATD) return;
  int b = (int)(i / FLATD);
  int r = (int)(i - (size_t)b*FLATD);
  int c = r >> 8, p = r & 255;
  int lw = lastw[b*256 + p];
  float lc = lastc[b*256 + p];
  float v;
  if (lw >= 0) v = H[(size_t)(lw*32 + b)*MAPD + c]*lc;
  else         v = ld<F32>(st0, i)*lc;
  if constexpr (F32) ((float*)out)[6144 + i] = v; else ((u16*)out)[6144 + i] = fbf(v);
}
__global__ __launch_bounds__(256) void k_final(const float* H, const void* st0,
                                               const int* lastw, const float* lastc, void* out,
                                               const int* flag){
  if (*flag) final_body<true>(H,st0,lastw,lastc,out); else final_body<false>(H,st0,lastw,lastc,out);
}

extern "C" void kernel_launch(void* const* d_in, const int* in_sizes, int n_in,
                              void* d_out, int out_size, void* d_ws, size_t ws_size,
                              hipStream_t stream) {
  (void)in_sizes; (void)n_in; (void)out_size; (void)ws_size;
  const void* image = d_in[0];
  const int*  lact  = (const int*)d_in[1];
  const int*  pos   = (const int*)d_in[2];
  const void* done  = d_in[3];
  const void* st0   = d_in[4];
  const void* c1w = d_in[5];  const void* c1b = d_in[6];
  const void* c2w = d_in[7];  const void* c2b = d_in[8];
  const void* c3w = d_in[9];  const void* c3b = d_in[10];
  const void* fcw = d_in[11]; const void* fcb = d_in[12];
  const void* pw1 = d_in[13]; const void* pb1 = d_in[14];
  const void* pw2 = d_in[15]; const void* pb2 = d_in[16];
  const void* vw1 = d_in[17]; const void* vb1 = d_in[18];
  const void* vw2 = d_in[19]; const void* vb2 = d_in[20];
  char* ws = (char*)d_ws;

  // workspace (~47.9 MB). WT overlays A/Bv/C (dead after fc).
  u16*   WT    = (u16*)  (ws + 0);           // 33,882,112
  u16*   A     = (u16*)  (ws + 0);
  u16*   Bv    = (u16*)  (ws + 14745600);
  u16*   C     = (u16*)  (ws + 19464192);
  float* H     = (float*)(ws + 33882368);    // +2,117,632
  float* YI    = (float*)(ws + 36000256);    // +16,384
  float* DLT4  = (float*)(ws + 36016640);    // +2,097,152
  int*   PREV  = (int*)  (ws + 38114048);
  float* COEF  = (float*)(ws + 38118144);
  int*   LASTW = (int*)  (ws + 38122240);
  float* LASTC = (float*)(ws + 38155008);
  int*   FLAG  = (int*)  (ws + 38187776);
  u16*   W1F   = (u16*)  (ws + 38188032);
  u16*   W2F   = (u16*)  (ws + 38200320);
  u16*   W3F   = (u16*)  (ws + 38265856);
  u16*   FWT   = (u16*)  (ws + 38339584);    // +1,048,576
  u16*   ST0T  = (u16*)  (ws + 39388416);    // +8,470,528 -> 47,858,944

  k_probe<<<1, 64, 0, stream>>>(image, FLAG);
  k_wprep<<<296, 256, 0, stream>>>(c1w, c2w, c3w, W1F, W2F, W3F, FLAG);
  k_fwt  <<<128, 256, 0, stream>>>(fcw, FWT, FLAG);
  k_st0t <<<260, 256, 0, stream>>>(st0, ST0T, FLAG);
  k_prev <<<4, 256, 0, stream>>>(pos, done, lact, PREV, COEF, H, YI, FLAG);
  k_last <<<32, 256, 0, stream>>>(pos, done, LASTW, LASTC, FLAG);
  k_conv1<<<1024, 256, 0, stream>>>(image, W1F, c1b, A, FLAG);
  k_conv2<<<1024, 256, 0, stream>>>(A, W2F, c2b, Bv, FLAG);
  k_conv3<<<1024, 256, 0, stream>>>(Bv, W3F, c3b, C, FLAG);
  k_fc   <<<256, 256, 0, stream>>>(C, FWT, fcb, H, FLAG);
  k_wt   <<<1034, 256, 0, stream>>>(pw1, vw1, WT, FLAG);
  k_yinit<<<1024, 256, 0, stream>>>(ST0T, WT, YI);
  k_delta<<<4096, 128, 0, stream>>>(H, WT, ST0T, pos, done, PREV, COEF, DLT4, FLAG);
  k_scan <<<32, 128, 0, stream>>>(YI, DLT4, done, pb1, vb1, pw2, pb2, vw2, vb2, d_out, FLAG);
  k_final<<<16544, 256, 0, stream>>>(H, st0, LASTW, LASTC, d_out, FLAG);
}

// Round 7
// 435.155 us; speedup vs baseline: 2.1099x; 1.1413x over previous
//
#include <hip/hip_runtime.h>

#define T_ 32
#define B_ 32
#define MAPD 517
#define P_ 256
#define FLATD (MAPD*P_)   // 132352
#define TBN (T_*B_)       // 1024

typedef unsigned short u16;
typedef unsigned int u32;
typedef __attribute__((ext_vector_type(4))) short short4v;
typedef __attribute__((ext_vector_type(8))) short short8v;
typedef __attribute__((ext_vector_type(4))) float f32x4;

__device__ __forceinline__ float bfv(u16 u){ u32 x = ((u32)u)<<16; return __uint_as_float(x); }
__device__ __forceinline__ u16 fbf(float f){
  u32 x = __float_as_uint(f);
  return (u16)((x + 0x7fffu + ((x>>16)&1u))>>16);
}
template<bool F32> __device__ __forceinline__ float ld(const void* p, size_t i){
  if constexpr (F32) return ((const float*)p)[i];
  else               return bfv(((const u16*)p)[i]);
}

// ---- dtype probe: 1 if float inputs are fp32, 0 if bf16 ----
__global__ void k_probe(const void* img, int* flag){
  if (threadIdx.x == 0 && blockIdx.x == 0){
    const u16* u = (const u16*)img;
    int cnt = 0;
    for (int i = 0; i < 256; ++i) if (u[i] <= 0x4380u) ++cnt;
    *flag = (cnt < 240) ? 1 : 0;
  }
}

// ---- K-prep (fused): conv frag layouts + FWT transpose + ST0T transpose ----
__global__ __launch_bounds__(256) void k_prep(const void* c1w, const void* c2w, const void* c3w,
                                              const void* fcw, const void* st0,
                                              u16* W1F, u16* W2F, u16* W3F, u16* FWT, u16* ST0T,
                                              const int* flag){
  __shared__ __align__(16) char smem_[32768];
  bool f32 = (*flag != 0);
  int bid = blockIdx.x, tid = threadIdx.x;
  if (bid < 24){
    int idx = bid*256 + tid;                   // 6144
    int j = idx & 7, l = (idx>>3) & 63, t = idx>>9;
    int nt = t/6, s = t - nt*6;
    int oc = nt*16 + (l&15);
    int kk = 8*(4*s + (l>>4)) + j;
    float v = f32 ? ((const float*)c1w)[oc*192+kk] : bfv(((const u16*)c1w)[oc*192+kk]);
    W1F[idx] = fbf(v);
  } else if (bid < 152){
    int idx = (bid-24)*256 + tid;              // 32768
    int j = idx & 7, l = (idx>>3) & 63, s = (idx>>9) & 15, nt = idx>>13;
    int oc = nt*16 + (l&15);
    int cin = (l>>4)*8 + j;
    int src = oc*512 + cin*16 + (s>>2)*4 + (s&3);
    float v = f32 ? ((const float*)c2w)[src] : bfv(((const u16*)c2w)[src]);
    W2F[idx] = fbf(v);
  } else if (bid < 296){
    int idx = (bid-152)*256 + tid;             // 36864
    int j = idx & 7, l = (idx>>3) & 63, t = idx>>9;   // t = nt*18+s
    int nt = t/18, s = t - nt*18;
    int oc = nt*16 + (l&15);
    int c = (s&1)*32 + (l>>4)*8 + j;
    int src = oc*576 + c*9 + (s>>1);
    float v = f32 ? ((const float*)c3w)[src] : bfv(((const u16*)c3w)[src]);
    W3F[idx] = fbf(v);
  } else if (bid < 424){
    // FWT tiled transpose: FWT[kk*512+o] = fcw[o*1024+k], kk=(k&15)*64+(k>>4)
    float* t = (float*)smem_;                  // 64*65*4 = 16,640 B
    int b = bid - 296;
    int o0 = (b >> 4)*64, k0 = (b & 15)*64;
    for (int it = 0; it < 16; ++it){
      int idx = it*256 + tid;
      int oo = idx >> 6, kk = idx & 63;
      float v = f32 ? ((const float*)fcw)[(size_t)(o0+oo)*1024 + k0+kk]
                    : bfv(((const u16*)fcw)[(size_t)(o0+oo)*1024 + k0+kk]);
      t[oo*65 + kk] = v;
    }
    __syncthreads();
    for (int it = 0; it < 16; ++it){
      int idx = it*256 + tid;
      int oo = idx & 63, dk = idx >> 6;
      int k = k0 + dk;
      int kk = (k & 15)*64 + (k >> 4);
      FWT[(size_t)kk*512 + o0 + oo] = fbf(t[oo*65 + dk]);
    }
  } else {
    // ST0T[p][c][b] transpose
    u16* tile = (u16*)smem_;                   // 32,768 B
    int b0 = bid - 424;                        // 260 blocks
    int c0 = (b0 >> 2)*8, p0 = (b0 & 3)*64;
    for (int it = 0; it < 64; ++it){
      int idx = it*256 + tid;
      int pl = idx & 63, b = (idx>>6)&31, ci = idx>>11;
      int c = c0 + ci;
      float v = 0.f;
      if (c < MAPD)
        v = f32 ? ((const float*)st0)[((size_t)b*MAPD+c)*256 + p0+pl]
                : bfv(((const u16*)st0)[((size_t)b*MAPD+c)*256 + p0+pl]);
      tile[ci*2048 + pl*32 + b] = fbf(v);
    }
    __syncthreads();
    for (int it = 0; it < 64; ++it){
      int idx = it*256 + tid;
      int b = idx & 31, ci = (idx>>5)&7, pl = idx>>8;
      int c = c0 + ci;
      if (c < MAPD)
        ST0T[((size_t)(p0+pl)*MAPD + c)*32 + b] = tile[ci*2048 + pl*32 + b];
    }
  }
}

// ---- K-meta (fused): prev-writer/coef + one-hot into H ; last-writer/coef ----
__global__ void k_meta(const int* pos, const void* done, const int* lact,
                       int* prev, float* coef, float* H, int* lastw, float* lastc, const int* flag){
  bool f32 = (*flag != 0);
  int bid = blockIdx.x;
  if (bid < 4){
    int i = bid*256 + threadIdx.x;
    int t = i >> 5, b = i & 31;
    int p = pos[i*2]*16 + pos[i*2+1];
    int pv = -1;
    for (int s = t-1; s >= 0; --s){
      int n = s*32 + b;
      if (pos[n*2]*16 + pos[n*2+1] == p){ pv = s; break; }
    }
    float cf = 1.f;
    for (int s = (pv<0?0:pv+1); s <= t-1; ++s)
      cf *= (1.f - (f32 ? ((const float*)done)[s*32+b] : bfv(((const u16*)done)[s*32+b])));
    prev[i] = pv; coef[i] = cf;
    int la = lact[i];
    #pragma unroll
    for (int a = 0; a < 5; ++a) H[(size_t)i*MAPD + 512 + a] = (la == a) ? 1.f : 0.f;
  } else {
    int i = (bid-4)*256 + threadIdx.x;
    int b = i >> 8, p = i & 255;
    int lw = -1;
    for (int s = T_-1; s >= 0; --s){
      int n = s*32 + b;
      if (pos[n*2]*16 + pos[n*2+1] == p){ lw = s; break; }
    }
    float cf = 1.f;
    for (int s = (lw<0?0:lw+1); s < T_; ++s)
      cf *= (1.f - (f32 ? ((const float*)done)[s*32+b] : bfv(((const u16*)done)[s*32+b])));
    lastw[i] = lw; lastc[i] = cf;
  }
}

// ---- K1: conv1 MFMA implicit GEMM. M=225 (16 tiles), N=32 (2 tiles), K=192 (6 steps) ----
__global__ __launch_bounds__(256) void k_conv1(const void* img, const u16* W1F, const void* bias,
                                               u16* out, const int* flag){
  __shared__ u16 sImg[12288];
  __shared__ u16 sWF[6144];
  __shared__ float sB[32];
  bool f32 = (*flag != 0);
  int n = blockIdx.x, tid = threadIdx.x;
  if (f32){
    const float4* ip = (const float4*)((const float*)img + (size_t)n*12288);
    for (int i = tid; i < 3072; i += 256){
      float4 v = ip[i];
      ushort4 u; u.x = fbf(v.x); u.y = fbf(v.y); u.z = fbf(v.z); u.w = fbf(v.w);
      *(ushort4*)(sImg + i*4) = u;
    }
  } else {
    const ushort4* ip = (const ushort4*)((const u16*)img + (size_t)n*12288);
    for (int i = tid; i < 3072; i += 256) *(ushort4*)(sImg + i*4) = ip[i];
  }
  { const ushort4* wf = (const ushort4*)W1F;
    for (int i = tid; i < 1536; i += 256) *(ushort4*)(sWF + i*4) = wf[i]; }
  if (tid < 32) sB[tid] = f32 ? ((const float*)bias)[tid] : bfv(((const u16*)bias)[tid]);
  __syncthreads();

  int wv = tid >> 6, lane = tid & 63;
  int mi = lane & 15, q = lane >> 4;

  short8v bfr[2][6];
  #pragma unroll
  for (int nt = 0; nt < 2; ++nt)
    #pragma unroll
    for (int s = 0; s < 6; ++s)
      bfr[nt][s] = *(const short8v*)(sWF + ((nt*6+s)*64 + lane)*8);

  f32x4 acc[4][2];
  #pragma unroll
  for (int mt = 0; mt < 4; ++mt)
    #pragma unroll
    for (int nt = 0; nt < 2; ++nt)
      acc[mt][nt] = (f32x4){0.f,0.f,0.f,0.f};

  int base[4];
  #pragma unroll
  for (int mt = 0; mt < 4; ++mt){
    int m = (wv*4+mt)*16 + mi;
    int mc = m < 225 ? m : 224;
    int oy = mc/15, ox = mc - oy*15;
    base[mt] = oy*256 + ox*4;
  }

  for (int s = 0; s < 6; ++s){
    int cky = 4*s + q;
    int off = (cky >> 3)*4096 + (cky & 7)*64;
    #pragma unroll
    for (int mt = 0; mt < 4; ++mt){
      const u16* ap = sImg + base[mt] + off;
      short4v lo = *(const short4v*)ap;
      short4v hi = *(const short4v*)(ap + 4);
      short8v a = __builtin_shufflevector(lo, hi, 0,1,2,3,4,5,6,7);
      acc[mt][0] = __builtin_amdgcn_mfma_f32_16x16x32_bf16(a, bfr[0][s], acc[mt][0], 0,0,0);
      acc[mt][1] = __builtin_amdgcn_mfma_f32_16x16x32_bf16(a, bfr[1][s], acc[mt][1], 0,0,0);
    }
  }

  u16* ob = out + (size_t)n*7200;
  #pragma unroll
  for (int mt = 0; mt < 4; ++mt){
    int mrow0 = (wv*4+mt)*16 + q*4;
    #pragma unroll
    for (int nt = 0; nt < 2; ++nt){
      int oc = nt*16 + mi;
      float bv = sB[oc];
      #pragma unroll
      for (int r = 0; r < 4; ++r){
        int m = mrow0 + r;
        if (m < 225) ob[m*32 + oc] = fbf(fmaxf(acc[mt][nt][r] + bv, 0.f));
      }
    }
  }
}

// ---- K2: conv2 MFMA implicit GEMM ----
__global__ __launch_bounds__(256) void k_conv2(const u16* __restrict__ A, const u16* __restrict__ W2F,
                                               const void* bias, u16* __restrict__ out, const int* flag){
  __shared__ u16 sIn[7200];
  bool f32 = (*flag != 0);
  int n = blockIdx.x, tid = threadIdx.x;
  const ushort4* ip = (const ushort4*)(A + (size_t)n*7200);
  for (int i = tid; i < 1800; i += 256) *(ushort4*)(sIn + i*4) = ip[i];
  int wv = tid >> 6, lane = tid & 63, mi = lane & 15, q = lane >> 4;

  short8v bfr[16];
  #pragma unroll
  for (int s = 0; s < 16; ++s)
    bfr[s] = ((const short8v*)W2F)[(wv*16+s)*64 + lane];

  int oc = wv*16 + mi;
  float bv = f32 ? ((const float*)bias)[oc] : bfv(((const u16*)bias)[oc]);
  f32x4 acc[3];
  #pragma unroll
  for (int mt = 0; mt < 3; ++mt) acc[mt] = (f32x4){0.f,0.f,0.f,0.f};
  int base[3];
  #pragma unroll
  for (int mt = 0; mt < 3; ++mt){
    int m = mt*16 + mi; if (m > 35) m = 35;
    int oy = m/6, ox = m - oy*6;
    base[mt] = (oy*30 + ox*2)*32;
  }
  __syncthreads();
  #pragma unroll
  for (int s = 0; s < 16; ++s){
    int off = ((s>>2)*15 + (s&3))*32 + q*8;
    #pragma unroll
    for (int mt = 0; mt < 3; ++mt){
      short8v a = *(const short8v*)(sIn + base[mt] + off);
      acc[mt] = __builtin_amdgcn_mfma_f32_16x16x32_bf16(a, bfr[s], acc[mt], 0,0,0);
    }
  }
  u16* ob = out + (size_t)n*2304;
  #pragma unroll
  for (int mt = 0; mt < 3; ++mt)
    #pragma unroll
    for (int r = 0; r < 4; ++r){
      int m = mt*16 + q*4 + r;
      if (m < 36) ob[m*64 + oc] = fbf(fmaxf(acc[mt][r] + bv, 0.f));
    }
}

// ---- K3: conv3 MFMA implicit GEMM ----
__global__ __launch_bounds__(256) void k_conv3(const u16* __restrict__ Bv, const u16* __restrict__ W3F,
                                               const void* bias, u16* __restrict__ out, const int* flag){
  __shared__ u16 sIn[2304];
  bool f32 = (*flag != 0);
  int n = blockIdx.x, tid = threadIdx.x;
  const ushort4* ip = (const ushort4*)(Bv + (size_t)n*2304);
  for (int i = tid; i < 576; i += 256) *(ushort4*)(sIn + i*4) = ip[i];
  int wv = tid >> 6, lane = tid & 63, mi = lane & 15, q = lane >> 4;
  int oy = mi >> 2, ox = mi & 3;
  int oc = wv*16 + mi;
  float bv = f32 ? ((const float*)bias)[oc] : bfv(((const u16*)bias)[oc]);

  short8v bfr[18];
  #pragma unroll
  for (int s = 0; s < 18; ++s)
    bfr[s] = ((const short8v*)W3F)[(wv*18+s)*64 + lane];

  f32x4 acc = (f32x4){0.f,0.f,0.f,0.f};
  __syncthreads();
  #pragma unroll
  for (int s = 0; s < 18; ++s){
    int pair = s >> 1, ky = pair/3, kx = pair - ky*3;
    int off = ((oy+ky)*6 + ox+kx)*64 + (s&1)*32 + q*8;
    short8v a = *(const short8v*)(sIn + off);
    acc = __builtin_amdgcn_mfma_f32_16x16x32_bf16(a, bfr[s], acc, 0,0,0);
  }
  u16* ob = out + (size_t)n*1024;
  #pragma unroll
  for (int r = 0; r < 4; ++r)
    ob[(q*4+r)*64 + oc] = fbf(fmaxf(acc[r] + bv, 0.f));
}

// ---- K4: fc GEMM 1024x512x1024 + ReLU -> H[samp][517] fp32 ----
template<bool F32> __device__ void fc_body(const u16* C, const u16* FWT, const void* fb,
                                           float* H, u16* sA, u16* sB){
  int tid = threadIdx.x;
  int s0 = (blockIdx.x >> 3)*32, o0 = (blockIdx.x & 7)*64;
  int si = tid & 15, ojg = tid >> 4;
  float acc[2][4];
  #pragma unroll
  for (int a = 0; a < 2; ++a)
    #pragma unroll
    for (int j = 0; j < 4; ++j) acc[a][j] = 0.f;

  for (int kc = 0; kc < 8; ++kc){
    __syncthreads();
    for (int it = 0; it < 16; ++it){
      int idx = it*256 + tid;
      int s = idx >> 7, kk = idx & 127;
      sA[kk*34 + s] = C[(size_t)(s0+s)*1024 + kc*128 + kk];
    }
    for (int it = 0; it < 32; ++it){
      int idx = it*256 + tid;
      int kk = idx >> 6, oj = idx & 63;
      sB[kk*64 + oj] = FWT[(size_t)(kc*128+kk)*512 + o0 + oj];
    }
    __syncthreads();
    for (int k = 0; k < 128; ++k){
      ushort2 a2 = *(const ushort2*)(sA + k*34 + si*2);
      ushort4 b4 = *(const ushort4*)(sB + k*64 + ojg*4);
      float a0 = bfv(a2.x), a1 = bfv(a2.y);
      float b0 = bfv(b4.x), b1 = bfv(b4.y), b2 = bfv(b4.z), b3 = bfv(b4.w);
      acc[0][0] += a0*b0; acc[0][1] += a0*b1; acc[0][2] += a0*b2; acc[0][3] += a0*b3;
      acc[1][0] += a1*b0; acc[1][1] += a1*b1; acc[1][2] += a1*b2; acc[1][3] += a1*b3;
    }
  }
  #pragma unroll
  for (int ss = 0; ss < 2; ++ss)
    #pragma unroll
    for (int j = 0; j < 4; ++j){
      int o = o0 + ojg*4 + j;
      H[(size_t)(s0 + si*2 + ss)*MAPD + o] = fmaxf(acc[ss][j] + ld<F32>(fb, o), 0.f);
    }
}
__global__ __launch_bounds__(256) void k_fc(const u16* C, const u16* FWT, const void* fb,
                                            float* H, const int* flag){
  __shared__ u16 sA[128*34];
  __shared__ u16 sB[128*64];
  if (*flag) fc_body<true>(C,FWT,fb,H,sA,sB); else fc_body<false>(C,FWT,fb,H,sA,sB);
}

// ---- K0: transpose w1 (128 x 132352) into WT[p][c][j] bf16 ----
template<bool F32> __device__ void wt_body(const void* pw1, const void* vw1, u16* wt, u16* tile){
  int c  = blockIdx.x >> 1;
  int ph = blockIdx.x & 1;
  for (int idx = threadIdx.x; idx < 16384; idx += 256){
    int j = idx >> 7, pp = idx & 127;
    const void* w = (j < 64) ? pw1 : vw1;
    int jj = (j < 64) ? j : j - 64;
    tile[pp*129 + j] = fbf(ld<F32>(w, (size_t)jj*FLATD + c*P_ + ph*128 + pp));
  }
  __syncthreads();
  for (int idx = threadIdx.x; idx < 16384; idx += 256){
    int pp = idx >> 7, j = idx & 127;
    int p = ph*128 + pp;
    wt[((size_t)p*MAPD + c)*128 + j] = tile[pp*129 + j];
  }
}
__global__ __launch_bounds__(256) void k_wt(const void* pw1, const void* vw1, u16* wt, const int* flag){
  __shared__ u16 tile[128*129];
  if (*flag) wt_body<true>(pw1,vw1,wt,tile); else wt_body<false>(pw1,vw1,wt,tile);
}

// ---- K6: y_init partials: PARTB[block][b][j] (bf16), no atomics ----
template<int CLEN>
__device__ __forceinline__ void yloop(const u16* __restrict__ wp, const float* __restrict__ sSb,
                                      float (&acc)[8][2]){
  #pragma unroll 10
  for (int c = 0; c < CLEN; ++c){
    u32 w = *(const u32*)(wp + (size_t)c*128);            // global, 256 B/wave, L1-shared
    float w0 = bfv((u16)(w & 0xffffu)), w1 = bfv((u16)(w >> 16));
    const float4* s4 = (const float4*)(sSb + c*32);       // LDS broadcast (free)
    float4 sa = s4[0], sb = s4[1];
    float sv[8] = {sa.x,sa.y,sa.z,sa.w,sb.x,sb.y,sb.z,sb.w};
    #pragma unroll
    for (int bb = 0; bb < 8; ++bb){
      acc[bb][0] += sv[bb]*w0;
      acc[bb][1] += sv[bb]*w1;
    }
  }
}
__global__ __launch_bounds__(256) void k_yinit(const u16* __restrict__ ST0T, const u16* __restrict__ wt,
                                               u16* __restrict__ PARTB){
  __shared__ float sS[130*32];   // 16.6 KB -> high occupancy
  int p = blockIdx.x >> 2, cq = blockIdx.x & 3;
  int c0 = cq*130;
  int clen = (cq == 3) ? 127 : 130;
  const ushort4* ssrc = (const ushort4*)(ST0T + ((size_t)p*MAPD + c0)*32);
  int n4 = clen*8;
  for (int i = threadIdx.x; i < n4; i += 256){
    ushort4 u = ssrc[i];
    float4 f; f.x = bfv(u.x); f.y = bfv(u.y); f.z = bfv(u.z); f.w = bfv(u.w);
    *(float4*)(sS + i*4) = f;
  }
  __syncthreads();
  int jg = threadIdx.x & 63, bg = threadIdx.x >> 6;
  int j0 = jg*2, b0 = bg*8;
  const u16* wp = wt + ((size_t)p*MAPD + c0)*128 + j0;
  float acc[8][2] = {};
  if (cq < 3) yloop<130>(wp, sS + b0, acc);
  else        yloop<127>(wp, sS + b0, acc);
  u32* op = (u32*)(PARTB + (size_t)blockIdx.x*4096);
  #pragma unroll
  for (int bb = 0; bb < 8; ++bb){
    u32 pk = (u32)fbf(acc[bb][0]) | ((u32)fbf(acc[bb][1]) << 16);
    op[((b0+bb)*128 + j0) >> 1] = pk;
  }
}

// ---- K6b: reduce 1024 partials -> YI (fp32) ----
__global__ __launch_bounds__(256) void k_yred(const u16* __restrict__ PARTB, float* __restrict__ YI){
  int o = blockIdx.x*64 + (threadIdx.x & 63);
  int kq = threadIdx.x >> 6;
  float s = 0.f;
  const u16* pp = PARTB + (size_t)kq*256*4096 + o;
  #pragma unroll 8
  for (int k = 0; k < 256; ++k) s += bfv(pp[(size_t)k*4096]);
  __shared__ float red[256];
  red[threadIdx.x] = s;
  __syncthreads();
  if (threadIdx.x < 64)
    YI[o] = red[threadIdx.x] + red[threadIdx.x+64] + red[threadIdx.x+128] + red[threadIdx.x+192];
}

// ---- K7: delta partial dots; grid (n x 4 c-chunks) -> DLT4[n*4+cq][j] ----
__global__ __launch_bounds__(128) void k_delta(const float* __restrict__ H, const u16* __restrict__ wt,
                                               const u16* __restrict__ st0t,
                                               const int* __restrict__ pos, const void* done,
                                               const int* __restrict__ prev, const float* __restrict__ coef,
                                               float* __restrict__ dlt4, const int* flag){
  __shared__ float diff[132];
  bool f32 = (*flag != 0);
  int n = blockIdx.x >> 2, cq = blockIdx.x & 3;
  int c0 = cq*130, clen = (cq == 3) ? 127 : 130;
  int b = n & 31;
  int p = pos[n*2]*16 + pos[n*2+1];
  float dn = f32 ? ((const float*)done)[n] : bfv(((const u16*)done)[n]);
  float m = 1.f - dn;
  int pv = prev[n];
  float cf = coef[n]*m;
  const float* hc = H + (size_t)n*MAPD + c0;
  for (int c = threadIdx.x; c < clen; c += 128){
    float old;
    if (pv >= 0) old = H[(size_t)(pv*32 + b)*MAPD + c0 + c];
    else         old = bfv(st0t[((size_t)p*MAPD + c0 + c)*32 + b]);
    diff[c] = hc[c] - cf*old;
  }
  __syncthreads();
  int j = threadIdx.x;
  const u16* wp = wt + ((size_t)p*MAPD + c0)*128 + j;
  float acc = 0.f;
  int c = 0;
  for (; c + 4 <= clen; c += 4){
    u16 w0 = wp[(size_t)c*128], w1 = wp[(size_t)(c+1)*128];
    u16 w2 = wp[(size_t)(c+2)*128], w3 = wp[(size_t)(c+3)*128];
    acc += diff[c]*bfv(w0) + diff[c+1]*bfv(w1) + diff[c+2]*bfv(w2) + diff[c+3]*bfv(w3);
  }
  for (; c < clen; ++c) acc += diff[c]*bfv(wp[(size_t)c*128]);
  dlt4[(size_t)blockIdx.x*128 + j] = acc;
}

// ---- K8: 32-step scan + head matvecs (sums 4 delta partials) ----
template<bool F32> __device__ void scan_body(const float* yi, const float* dlt4, const void* done,
                                             const void* pb1, const void* vb1,
                                             const void* pw2, const void* pb2,
                                             const void* vw2, const void* vb2, void* out,
                                             float* th){
  int b = blockIdx.x, j = threadIdx.x;
  float y = yi[b*128 + j];
  float bias = (j < 64) ? ld<F32>(pb1, j) : ld<F32>(vb1, j-64);
  for (int t = 0; t < T_; ++t){
    int n = t*32 + b;
    float m = 1.f - ld<F32>(done, n);
    const float* dp = dlt4 + (size_t)n*4*128 + j;
    float d = dp[0] + dp[128] + dp[256] + dp[384];
    y = m*y + d;
    th[j] = tanhf(y + bias);
    __syncthreads();
    if (j < 5){
      float s = ld<F32>(pb2, j);
      for (int q = 0; q < 64; ++q) s += th[q]*ld<F32>(pw2, j*64 + q);
      if constexpr (F32) ((float*)out)[n*5 + j] = s; else ((u16*)out)[n*5 + j] = fbf(s);
    } else if (j == 5){
      float s = ld<F32>(vb2, 0);
      for (int q = 0; q < 64; ++q) s += th[64 + q]*ld<F32>(vw2, q);
      if constexpr (F32) ((float*)out)[5120 + n] = s; else ((u16*)out)[5120 + n] = fbf(s);
    }
    __syncthreads();
  }
}
__global__ __launch_bounds__(128) void k_scan(const float* yi, const float* dlt4, const void* done,
                                              const void* pb1, const void* vb1,
                                              const void* pw2, const void* pb2,
                                              const void* vw2, const void* vb2, void* out,
                                              const int* flag){
  __shared__ float th[128];
  if (*flag) scan_body<true>(yi,dlt4,done,pb1,vb1,pw2,pb2,vw2,vb2,out,th);
  else       scan_body<false>(yi,dlt4,done,pb1,vb1,pw2,pb2,vw2,vb2,out,th);
}

// ---- K9: final_state closed form ----
template<bool F32> __device__ void final_body(const float* H, const void* st0,
                                              const int* lastw, const float* lastc, void* out){
  size_t i = (size_t)blockIdx.x*256 + threadIdx.x;
  if (i >= (size_t)B_*FLATD) return;
  int b = (int)(i / FLATD);
  int r = (int)(i - (size_t)b*FLATD);
  int c = r >> 8, p = r & 255;
  int lw = lastw[b*256 + p];
  float lc = lastc[b*256 + p];
  float v;
  if (lw >= 0) v = H[(size_t)(lw*32 + b)*MAPD + c]*lc;
  else         v = ld<F32>(st0, i)*lc;
  if constexpr (F32) ((float*)out)[6144 + i] = v; else ((u16*)out)[6144 + i] = fbf(v);
}
__global__ __launch_bounds__(256) void k_final(const float* H, const void* st0,
                                               const int* lastw, const float* lastc, void* out,
                                               const int* flag){
  if (*flag) final_body<true>(H,st0,lastw,lastc,out); else final_body<false>(H,st0,lastw,lastc,out);
}

extern "C" void kernel_launch(void* const* d_in, const int* in_sizes, int n_in,
                              void* d_out, int out_size, void* d_ws, size_t ws_size,
                              hipStream_t stream) {
  (void)in_sizes; (void)n_in; (void)out_size; (void)ws_size;
  const void* image = d_in[0];
  const int*  lact  = (const int*)d_in[1];
  const int*  pos   = (const int*)d_in[2];
  const void* done  = d_in[3];
  const void* st0   = d_in[4];
  const void* c1w = d_in[5];  const void* c1b = d_in[6];
  const void* c2w = d_in[7];  const void* c2b = d_in[8];
  const void* c3w = d_in[9];  const void* c3b = d_in[10];
  const void* fcw = d_in[11]; const void* fcb = d_in[12];
  const void* pw1 = d_in[13]; const void* pb1 = d_in[14];
  const void* pw2 = d_in[15]; const void* pb2 = d_in[16];
  const void* vw1 = d_in[17]; const void* vb1 = d_in[18];
  const void* vw2 = d_in[19]; const void* vb2 = d_in[20];
  char* ws = (char*)d_ws;

  // workspace (~54.1 MB). WT overlays A/Bv/C; DLT4 overlays PARTB (dead after k_yred).
  u16*   WT    = (u16*)  (ws + 0);           // 33,882,112
  u16*   A     = (u16*)  (ws + 0);
  u16*   Bv    = (u16*)  (ws + 14745600);
  u16*   C     = (u16*)  (ws + 19464192);
  float* H     = (float*)(ws + 33882368);    // 2,117,632
  float* YI    = (float*)(ws + 36000256);    // 16,384
  u16*   PARTB = (u16*)  (ws + 36016640);    // 8,388,608 (1024*4096 bf16)
  float* DLT4  = (float*)(ws + 36016640);    // 2,097,152 (overlays PARTB, used after yred)
  int*   PREV  = (int*)  (ws + 44405248);
  float* COEF  = (float*)(ws + 44409344);
  int*   LASTW = (int*)  (ws + 44413440);
  float* LASTC = (float*)(ws + 44446208);
  int*   FLAG  = (int*)  (ws + 44478976);
  u16*   W1F   = (u16*)  (ws + 44479232);    // 12,288
  u16*   W2F   = (u16*)  (ws + 44491520);    // 65,536
  u16*   W3F   = (u16*)  (ws + 44557056);    // 73,728
  u16*   FWT   = (u16*)  (ws + 44630784);    // 1,048,576
  u16*   ST0T  = (u16*)  (ws + 45679360);    // 8,470,528 -> 54,149,888

  k_probe<<<1, 64, 0, stream>>>(image, FLAG);
  k_prep <<<684, 256, 0, stream>>>(c1w, c2w, c3w, fcw, st0, W1F, W2F, W3F, FWT, ST0T, FLAG);
  k_meta <<<36, 256, 0, stream>>>(pos, done, lact, PREV, COEF, H, LASTW, LASTC, FLAG);
  k_conv1<<<1024, 256, 0, stream>>>(image, W1F, c1b, A, FLAG);
  k_conv2<<<1024, 256, 0, stream>>>(A, W2F, c2b, Bv, FLAG);
  k_conv3<<<1024, 256, 0, stream>>>(Bv, W3F, c3b, C, FLAG);
  k_fc   <<<256, 256, 0, stream>>>(C, FWT, fcb, H, FLAG);
  k_wt   <<<1034, 256, 0, stream>>>(pw1, vw1, WT, FLAG);
  k_yinit<<<1024, 256, 0, stream>>>(ST0T, WT, PARTB);
  k_yred <<<64, 256, 0, stream>>>(PARTB, YI);
  k_delta<<<4096, 128, 0, stream>>>(H, WT, ST0T, pos, done, PREV, COEF, DLT4, FLAG);
  k_scan <<<32, 128, 0, stream>>>(YI, DLT4, done, pb1, vb1, pw2, pb2, vw2, vb2, d_out, FLAG);
  k_final<<<16544, 256, 0, stream>>>(H, st0, LASTW, LASTC, d_out, FLAG);
}